// Round 1
// baseline (1750.348 us; speedup 1.0000x reference)
//
#include <hip/hip_runtime.h>

typedef unsigned short u16;
typedef unsigned int   u32;
typedef __attribute__((ext_vector_type(8))) __bf16 bf16x8;
typedef __attribute__((ext_vector_type(4))) float  f32x4;
typedef __attribute__((ext_vector_type(4))) u16    u16x4;

#define DEV __device__ __forceinline__

// ---------- helpers ----------
DEV u16 f2b(float f) {               // fp32 -> bf16 bits, RNE
  union { float f; u32 u; } a; a.f = f;
  const u32 u = a.u;
  return (u16)((u + 0x7fffu + ((u >> 16) & 1u)) >> 16);
}

DEV void gload16(const void* g, void* l) {
  __builtin_amdgcn_global_load_lds(
      (const __attribute__((address_space(1))) void*)g,
      (__attribute__((address_space(3))) void*)l, 16, 0, 0);
}

// ---------- weight conversion (fp32 -> bf16) ----------
__global__ __launch_bounds__(256)
void conv_weights(const float* __restrict__ qkvw, const float* __restrict__ projw,
                  const float* __restrict__ w1,   const float* __restrict__ w2,
                  u16* __restrict__ dq, u16* __restrict__ dp,
                  u16* __restrict__ d1, u16* __restrict__ d2) {
  const int t = blockIdx.x * 256 + threadIdx.x;
  if (t < 196608)      dq[t]          = f2b(qkvw[t]);
  else if (t < 262144) dp[t - 196608] = f2b(projw[t - 196608]);
  else if (t < 524288) d1[t - 262144] = f2b(w1[t - 262144]);
  else                 d2[t - 524288] = f2b(w2[t - 524288]);
}

// ---------- window gather + LN1 ----------
// writes h (bf16, [m][256]) and xw residual copy (fp32, [m][256])
__global__ __launch_bounds__(256)
void ln1_win(const float* __restrict__ x, const float* __restrict__ w1,
             const float* __restrict__ b1, u16* __restrict__ hout,
             float* __restrict__ xwout) {
  __shared__ float xt[256 * 65];
  __shared__ float ps[4][64], pq[4][64];
  __shared__ float smean[64], srstd[64];
  const int tid = threadIdx.x, lane = tid & 63, wv = tid >> 6;
  const int r = blockIdx.x;
  const int b = r / 784, mm = r % 784;
  const int wh = mm / 28, ww = mm % 28;
  int hp = wh * 8 + (lane >> 3) + 4; if (hp >= 224) hp -= 224;
  int wp = ww * 8 + (lane & 7) + 4;  if (wp >= 224) wp -= 224;
  const int off = hp * 224 + wp;
  const float* xb = x + (long)b * 256 * 50176;
  float s0 = 0.f, q0 = 0.f;
#pragma unroll 8
  for (int i = 0; i < 64; ++i) {
    const int c = i * 4 + wv;
    const float v = xb[(long)c * 50176 + off];
    xt[c * 65 + lane] = v;
    s0 += v; q0 += v * v;
  }
  ps[wv][lane] = s0; pq[wv][lane] = q0;
  __syncthreads();
  if (tid < 64) {
    const float s = ps[0][tid] + ps[1][tid] + ps[2][tid] + ps[3][tid];
    const float q = pq[0][tid] + pq[1][tid] + pq[2][tid] + pq[3][tid];
    const float mean = s * (1.f / 256.f);
    const float var  = q * (1.f / 256.f) - mean * mean;
    smean[tid] = mean;
    srstd[tid] = rsqrtf(var + 1e-5f);
  }
  __syncthreads();
  const float wgt = w1[tid];
  const float bgt = b1[tid];
  const long base = (long)r * 64 * 256;
#pragma unroll 4
  for (int n = 0; n < 64; ++n) {
    const float v = xt[tid * 65 + n];
    xwout[base + n * 256 + tid] = v;
    hout[base + n * 256 + tid]  = f2b((v - smean[n]) * srstd[n] * wgt + bgt);
  }
}

// ---------- generic 128x128x(BK=64) bf16 GEMM, B given as [N][K] ----------
// EPI 0: qkv scatter (bout = qkv base; q | k | v at +0 / +51380224 / +102760448)
// EPI 1: y[m][n] += acc + bias[n]          (fout = y, ldc=256)
// EPI 2: hidden[m][n] = bf16(gelu(acc+b))  (bout = hidden, ldc=1024)
// EPI 3: y[m][n] += acc + bias[n]          (fout = y, ldc=256)
template<int EPI>
__global__ __launch_bounds__(256)
void gemm_bt(const u16* __restrict__ A, const u16* __restrict__ Bw, const int K,
             float* __restrict__ fout, const float* __restrict__ bias,
             u16* __restrict__ bout) {
  __shared__ u16 sA[128 * 64];
  __shared__ u16 sB[128 * 64];
  const int tid  = threadIdx.x;
  const int lane = tid & 63;
  const int wid  = tid >> 6;
  const int wr   = wid >> 1;
  const int wc   = wid & 1;
  const int row0 = blockIdx.x * 128;
  const int col0 = blockIdx.y * 128;

  const f32x4 vzero = {0.f, 0.f, 0.f, 0.f};
  f32x4 acc[4][4];
#pragma unroll
  for (int i = 0; i < 4; ++i)
#pragma unroll
    for (int j = 0; j < 4; ++j) acc[i][j] = vzero;

  const int lrow = lane >> 3;
  const int lcol = (lane & 7) << 3;
  const int l15  = lane & 15;
  const int l4   = lane >> 4;

  for (int kt = 0; kt < K; kt += 64) {
#pragma unroll
    for (int ch = 0; ch < 4; ++ch) {
      const int rr = (ch * 4 + wid) * 8;
      gload16(A  + (long)(row0 + rr + lrow) * K + kt + lcol, sA + rr * 64);
      gload16(Bw + (long)(col0 + rr + lrow) * K + kt + lcol, sB + rr * 64);
    }
    __syncthreads();
#pragma unroll
    for (int kk = 0; kk < 2; ++kk) {
      bf16x8 af[4], bfv[4];
#pragma unroll
      for (int mi = 0; mi < 4; ++mi)
        af[mi] = *(const bf16x8*)(sA + (wr * 64 + mi * 16 + l15) * 64 + kk * 32 + l4 * 8);
#pragma unroll
      for (int nj = 0; nj < 4; ++nj)
        bfv[nj] = *(const bf16x8*)(sB + (wc * 64 + nj * 16 + l15) * 64 + kk * 32 + l4 * 8);
#pragma unroll
      for (int mi = 0; mi < 4; ++mi)
#pragma unroll
        for (int nj = 0; nj < 4; ++nj)
          acc[mi][nj] = __builtin_amdgcn_mfma_f32_16x16x32_bf16(af[mi], bfv[nj], acc[mi][nj], 0, 0, 0);
    }
    __syncthreads();
  }

#pragma unroll
  for (int mi = 0; mi < 4; ++mi)
#pragma unroll
    for (int nj = 0; nj < 4; ++nj)
#pragma unroll
      for (int reg = 0; reg < 4; ++reg) {
        const int m = row0 + wr * 64 + mi * 16 + (l4 << 2) + reg;
        const int n = col0 + wc * 64 + nj * 16 + l15;
        const float v = acc[mi][nj][reg];
        if (EPI == 0) {
          const int rr = m >> 6, ii = m & 63;
          const int s = n >> 8, hh = (n >> 5) & 7, d = n & 31;
          long idx;
          if (s == 2) idx = 102760448L + (long)((rr * 8 + hh) * 32 + d) * 64 + ii; // v^T
          else        idx = (long)s * 51380224L + (long)((rr * 8 + hh) * 64 + ii) * 32 + d;
          bout[idx] = f2b(v);
        } else if (EPI == 1 || EPI == 3) {
          float* yp = fout + (long)m * 256 + n;
          *yp = *yp + v + bias[n];
        } else if (EPI == 2) {
          float g = v + bias[n];
          g = 0.5f * g * (1.0f + erff(g * 0.70710678118654752f));
          bout[(long)m * 1024 + n] = f2b(g);
        }
      }
}

// ---------- per-window attention ----------
__global__ __launch_bounds__(256)
void attn_win(const u16* __restrict__ qkv, const float* __restrict__ rpb,
              u16* __restrict__ aout) {
  __shared__ float Pls[4][64 * 66];
  __shared__ float srpb[1800];
  const int tid = threadIdx.x, lane = tid & 63, wv = tid >> 6;
  const int r = blockIdx.x;
  for (int i = tid; i < 1800; i += 256) srpb[i] = rpb[i];
  __syncthreads();

  // reference quirk: jnp.repeat(mask, B, axis=0) -> window r uses mask[r/4]
  const int midx = r >> 2;
  const int wh = midx / 28, ww = midx % 28;
  const int l15 = lane & 15, l4 = lane >> 4;

  float* Pw = &Pls[wv][0];
  const u16* kb = qkv + 51380224;
  const u16* vb = qkv + 102760448;

  int rj[4], cj[4], labj[4];
#pragma unroll
  for (int nj = 0; nj < 4; ++nj) {
    const int j = nj * 16 + l15;
    rj[nj] = j >> 3; cj[nj] = j & 7;
    const int hp = wh * 8 + rj[nj], wp = ww * 8 + cj[nj];
    const int lh = (hp < 216) ? 0 : ((hp < 220) ? 1 : 2);
    const int lw = (wp < 216) ? 0 : ((wp < 220) ? 1 : 2);
    labj[nj] = lh * 3 + lw;
  }

  const f32x4 vzero = {0.f, 0.f, 0.f, 0.f};
  for (int hh = 0; hh < 2; ++hh) {
    const int h = wv * 2 + hh;
    const long hb = (long)(r * 8 + h) * 2048;
    const u16* qh = qkv + hb;
    const u16* kh = kb + hb;
    const u16* vh = vb + hb;

    bf16x8 qf[4], kf[4];
#pragma unroll
    for (int mi = 0; mi < 4; ++mi)
      qf[mi] = *(const bf16x8*)(qh + (mi * 16 + l15) * 32 + l4 * 8);
#pragma unroll
    for (int nj = 0; nj < 4; ++nj)
      kf[nj] = *(const bf16x8*)(kh + (nj * 16 + l15) * 32 + l4 * 8);

    f32x4 S[4][4];
#pragma unroll
    for (int mi = 0; mi < 4; ++mi)
#pragma unroll
      for (int nj = 0; nj < 4; ++nj)
        S[mi][nj] = __builtin_amdgcn_mfma_f32_16x16x32_bf16(qf[mi], kf[nj], vzero, 0, 0, 0);

    float rsave[4][4];
#pragma unroll
    for (int mi = 0; mi < 4; ++mi)
#pragma unroll
      for (int reg = 0; reg < 4; ++reg) {
        const int i = mi * 16 + (l4 << 2) + reg;
        const int ri = i >> 3, ci = i & 7;
        const int hp = wh * 8 + ri, wp = ww * 8 + ci;
        const int lh = (hp < 216) ? 0 : ((hp < 220) ? 1 : 2);
        const int lw = (wp < 216) ? 0 : ((wp < 220) ? 1 : 2);
        const int li = lh * 3 + lw;
        float v[4];
#pragma unroll
        for (int nj = 0; nj < 4; ++nj) {
          const int idx = (ri - rj[nj] + 7) * 15 + (ci - cj[nj] + 7);
          v[nj] = S[mi][nj][reg] * 0.17677669529663687f + srpb[idx * 8 + h]
                + ((li != labj[nj]) ? -100.0f : 0.0f);
        }
        float mx = fmaxf(fmaxf(v[0], v[1]), fmaxf(v[2], v[3]));
        mx = fmaxf(mx, __shfl_xor(mx, 1));
        mx = fmaxf(mx, __shfl_xor(mx, 2));
        mx = fmaxf(mx, __shfl_xor(mx, 4));
        mx = fmaxf(mx, __shfl_xor(mx, 8));
        float sum = 0.f;
#pragma unroll
        for (int nj = 0; nj < 4; ++nj) { v[nj] = __expf(v[nj] - mx); sum += v[nj]; }
        sum += __shfl_xor(sum, 1);
        sum += __shfl_xor(sum, 2);
        sum += __shfl_xor(sum, 4);
        sum += __shfl_xor(sum, 8);
        rsave[mi][reg] = 1.0f / sum;          // deferred normalization
#pragma unroll
        for (int nj = 0; nj < 4; ++nj) Pw[i * 66 + nj * 16 + l15] = v[nj];
      }

    f32x4 O[4][2];
#pragma unroll
    for (int mi = 0; mi < 4; ++mi) { O[mi][0] = vzero; O[mi][1] = vzero; }
#pragma unroll
    for (int kk = 0; kk < 2; ++kk) {
      bf16x8 pf[4], vf[2];
#pragma unroll
      for (int mi = 0; mi < 4; ++mi) {
        const int base = (mi * 16 + l15) * 66 + kk * 32 + l4 * 8;
        bf16x8 t;
#pragma unroll
        for (int e = 0; e < 8; ++e) t[e] = (__bf16)Pw[base + e];
        pf[mi] = t;
      }
#pragma unroll
      for (int nd = 0; nd < 2; ++nd)
        vf[nd] = *(const bf16x8*)(vh + (nd * 16 + l15) * 64 + kk * 32 + l4 * 8);
#pragma unroll
      for (int mi = 0; mi < 4; ++mi)
#pragma unroll
        for (int nd = 0; nd < 2; ++nd)
          O[mi][nd] = __builtin_amdgcn_mfma_f32_16x16x32_bf16(pf[mi], vf[nd], O[mi][nd], 0, 0, 0);
    }

#pragma unroll
    for (int mi = 0; mi < 4; ++mi)
#pragma unroll
      for (int nd = 0; nd < 2; ++nd)
#pragma unroll
        for (int reg = 0; reg < 4; ++reg) {
          const int i = mi * 16 + (l4 << 2) + reg;
          aout[(long)(r * 64 + i) * 256 + h * 32 + nd * 16 + l15] =
              f2b(O[mi][nd][reg] * rsave[mi][reg]);
        }
  }
}

// ---------- rowwise LN2 ----------
__global__ __launch_bounds__(256)
void ln2_rows(const float* __restrict__ y, const float* __restrict__ w,
              const float* __restrict__ bb, u16* __restrict__ out) {
  const int lane = threadIdx.x & 63;
  const long row = (long)blockIdx.x * 4 + (threadIdx.x >> 6);
  const float4 v = *(const float4*)(y + row * 256 + lane * 4);
  float s = v.x + v.y + v.z + v.w;
  float q = v.x * v.x + v.y * v.y + v.z * v.z + v.w * v.w;
#pragma unroll
  for (int d = 1; d < 64; d <<= 1) { s += __shfl_xor(s, d); q += __shfl_xor(q, d); }
  const float mean = s * (1.f / 256.f);
  const float rstd = rsqrtf(q * (1.f / 256.f) - mean * mean + 1e-5f);
  const int c = lane * 4;
  u16x4 o;
  o[0] = f2b((v.x - mean) * rstd * w[c + 0] + bb[c + 0]);
  o[1] = f2b((v.y - mean) * rstd * w[c + 1] + bb[c + 1]);
  o[2] = f2b((v.z - mean) * rstd * w[c + 2] + bb[c + 2]);
  o[3] = f2b((v.w - mean) * rstd * w[c + 3] + bb[c + 3]);
  *(u16x4*)(out + row * 256 + c) = o;
}

// ---------- un-window scatter ----------
__global__ __launch_bounds__(256)
void unwin(const float* __restrict__ y, float* __restrict__ out) {
  __shared__ float t[256 * 65];
  const int tid = threadIdx.x, lane = tid & 63, wv = tid >> 6;
  const int r = blockIdx.x;
  const int b = r / 784, mm = r % 784;
  const int wh = mm / 28, ww = mm % 28;
  const long base = (long)r * 64 * 256;
#pragma unroll 8
  for (int n = 0; n < 64; ++n)
    t[tid * 65 + n] = y[base + n * 256 + tid];
  __syncthreads();
  int hp = wh * 8 + (lane >> 3) + 4; if (hp >= 224) hp -= 224;
  int wp = ww * 8 + (lane & 7) + 4;  if (wp >= 224) wp -= 224;
  const int off = hp * 224 + wp;
  float* ob = out + (long)b * 256 * 50176;
#pragma unroll 8
  for (int i = 0; i < 64; ++i) {
    const int c = i * 4 + wv;
    ob[(long)c * 50176 + off] = t[c * 65 + lane];
  }
}

// ---------- launch ----------
extern "C" void kernel_launch(void* const* d_in, const int* in_sizes, int n_in,
                              void* d_out, int out_size, void* d_ws, size_t ws_size,
                              hipStream_t stream) {
  (void)in_sizes; (void)n_in; (void)out_size; (void)ws_size;
  const float* x     = (const float*)d_in[0];
  const float* qkvw  = (const float*)d_in[1];
  const float* projw = (const float*)d_in[2];
  const float* projb = (const float*)d_in[3];
  const float* rpb   = (const float*)d_in[4];
  const float* n1w   = (const float*)d_in[5];
  const float* n1b   = (const float*)d_in[6];
  const float* n2w   = (const float*)d_in[7];
  const float* n2b   = (const float*)d_in[8];
  const float* w1    = (const float*)d_in[9];
  const float* b1    = (const float*)d_in[10];
  const float* w2    = (const float*)d_in[11];
  const float* b2    = (const float*)d_in[12];

  char* ws = (char*)d_ws;
  u16*   hbuf   = (u16*)(ws);                  // 102,760,448 B : h, later h2
  u16*   qkvb   = (u16*)(ws + 102760448);      // 308,281,344 B : q|k|v
  u16*   abuf   = (u16*)(ws + 411041792);      // 102,760,448 B : attn out
  float* ybuf   = (float*)(ws + 513802240);    // 205,520,896 B : fp32 residual stream
  u16*   hidb   = (u16*)(ws + 102760448);      // 411,041,792 B : overlays qkv+attn (dead by then)
  u16*   qkvwb  = (u16*)(ws + 719323136);
  u16*   projwb = (u16*)(ws + 719716352);
  u16*   w1b    = (u16*)(ws + 719847424);
  u16*   w2b    = (u16*)(ws + 720371712);      // end: 720,896,000 B

  conv_weights<<<3072, 256, 0, stream>>>(qkvw, projw, w1, w2, qkvwb, projwb, w1b, w2b);
  ln1_win<<<3136, 256, 0, stream>>>(x, n1w, n1b, hbuf, ybuf);
  gemm_bt<0><<<dim3(1568, 6), 256, 0, stream>>>(hbuf, qkvwb, 256, nullptr, nullptr, qkvb);
  attn_win<<<3136, 256, 0, stream>>>(qkvb, rpb, abuf);
  gemm_bt<1><<<dim3(1568, 2), 256, 0, stream>>>(abuf, projwb, 256, ybuf, projb, nullptr);
  ln2_rows<<<50176, 256, 0, stream>>>(ybuf, n2w, n2b, hbuf);
  gemm_bt<2><<<dim3(1568, 8), 256, 0, stream>>>(hbuf, w1b, 256, nullptr, b1, hidb);
  gemm_bt<3><<<dim3(1568, 2), 256, 0, stream>>>(hidb, w2b, 1024, ybuf, b2, nullptr);
  unwin<<<3136, 256, 0, stream>>>(ybuf, (float*)d_out);
}

// Round 2
// 1561.241 us; speedup vs baseline: 1.1211x; 1.1211x over previous
//
#include <hip/hip_runtime.h>

typedef unsigned short u16;
typedef unsigned int   u32;
typedef __attribute__((ext_vector_type(8))) __bf16 bf16x8;
typedef __attribute__((ext_vector_type(4))) float  f32x4;
typedef __attribute__((ext_vector_type(4))) u16    u16x4;
typedef __attribute__((ext_vector_type(8))) u16    u16x8;

#define DEV __device__ __forceinline__

// ---------- helpers ----------
DEV u16 f2b(float f) {               // fp32 -> bf16 bits, RNE
  union { float f; u32 u; } a; a.f = f;
  const u32 u = a.u;
  return (u16)((u + 0x7fffu + ((u >> 16) & 1u)) >> 16);
}

DEV void gload16(const void* g, void* l) {
  __builtin_amdgcn_global_load_lds(
      (const __attribute__((address_space(1))) void*)g,
      (__attribute__((address_space(3))) void*)l, 16, 0, 0);
}

// ---------- weight conversion (fp32 -> bf16) ----------
__global__ __launch_bounds__(256)
void conv_weights(const float* __restrict__ qkvw, const float* __restrict__ projw,
                  const float* __restrict__ w1,   const float* __restrict__ w2,
                  u16* __restrict__ dq, u16* __restrict__ dp,
                  u16* __restrict__ d1, u16* __restrict__ d2) {
  const int t = blockIdx.x * 256 + threadIdx.x;
  if (t < 196608)      dq[t]          = f2b(qkvw[t]);
  else if (t < 262144) dp[t - 196608] = f2b(projw[t - 196608]);
  else if (t < 524288) d1[t - 262144] = f2b(w1[t - 262144]);
  else                 d2[t - 524288] = f2b(w2[t - 524288]);
}

// ---------- window gather + LN1 ----------
__global__ __launch_bounds__(256)
void ln1_win(const float* __restrict__ x, const float* __restrict__ w1,
             const float* __restrict__ b1, u16* __restrict__ hout,
             float* __restrict__ xwout) {
  __shared__ float xt[256 * 65];
  __shared__ float ps[4][64], pq[4][64];
  __shared__ float smean[64], srstd[64];
  const int tid = threadIdx.x, lane = tid & 63, wv = tid >> 6;
  const int r = blockIdx.x;
  const int b = r / 784, mm = r % 784;
  const int wh = mm / 28, ww = mm % 28;
  int hp = wh * 8 + (lane >> 3) + 4; if (hp >= 224) hp -= 224;
  int wp = ww * 8 + (lane & 7) + 4;  if (wp >= 224) wp -= 224;
  const int off = hp * 224 + wp;
  const float* xb = x + (long)b * 256 * 50176;
  float s0 = 0.f, q0 = 0.f;
#pragma unroll 8
  for (int i = 0; i < 64; ++i) {
    const int c = i * 4 + wv;
    const float v = xb[(long)c * 50176 + off];
    xt[c * 65 + lane] = v;
    s0 += v; q0 += v * v;
  }
  ps[wv][lane] = s0; pq[wv][lane] = q0;
  __syncthreads();
  if (tid < 64) {
    const float s = ps[0][tid] + ps[1][tid] + ps[2][tid] + ps[3][tid];
    const float q = pq[0][tid] + pq[1][tid] + pq[2][tid] + pq[3][tid];
    const float mean = s * (1.f / 256.f);
    const float var  = q * (1.f / 256.f) - mean * mean;
    smean[tid] = mean;
    srstd[tid] = rsqrtf(var + 1e-5f);
  }
  __syncthreads();
  const float wgt = w1[tid];
  const float bgt = b1[tid];
  const long base = (long)r * 64 * 256;
#pragma unroll 4
  for (int n = 0; n < 64; ++n) {
    const float v = xt[tid * 65 + n];
    xwout[base + n * 256 + tid] = v;
    hout[base + n * 256 + tid]  = f2b((v - smean[n]) * srstd[n] * wgt + bgt);
  }
}

// ---------- generic 128x128x(BK=64) bf16 GEMM, B given as [N][K] ----------
// 1-D grid, XCD-chunk swizzle + column-fast decode (A-tile L2 reuse).
// LDS k-slot XOR swizzle (T2): LDS[R][slot] holds global k-slot (slot ^ (R&7)).
// EPI 0: qkv scatter (q | k | v^T); v^T via per-wave LDS transpose
// EPI 1/3: y[m][n] += acc + bias[n]
// EPI 2: hidden[m][n] = bf16(gelu(acc+b)), ldc=1024
template<int EPI, int NCOL>
__global__ __launch_bounds__(256)
void gemm_bt(const u16* __restrict__ A, const u16* __restrict__ Bw, const int K,
             float* __restrict__ fout, const float* __restrict__ bias,
             u16* __restrict__ bout) {
  __shared__ __align__(16) u16 smem[(EPI == 0) ? (4 * 64 * 72) : (2 * 128 * 64)];
  u16* sA = smem;
  u16* sB = smem + 128 * 64;

  const int tid  = threadIdx.x;
  const int lane = tid & 63;
  const int wid  = tid >> 6;
  const int wr   = wid >> 1;
  const int wc   = wid & 1;

  const int nwg = gridDim.x;
  const int bid = blockIdx.x;
  const int wg  = (bid & 7) * (nwg >> 3) + (bid >> 3);   // XCD chunk swizzle
  const int row_blk = wg / NCOL;                          // column-fast
  const int col_blk = wg - row_blk * NCOL;
  const int row0 = row_blk * 128;
  const int col0 = col_blk * 128;

  const f32x4 vzero = {0.f, 0.f, 0.f, 0.f};
  f32x4 acc[4][4];
#pragma unroll
  for (int i = 0; i < 4; ++i)
#pragma unroll
    for (int j = 0; j < 4; ++j) acc[i][j] = vzero;

  const int lrow = lane >> 3;
  const int lcol = ((lane & 7) << 3) ^ (lane & 56);  // pre-swizzled source k-offset
  const int l15  = lane & 15;
  const int l4   = lane >> 4;
  const int ksw  = (lane & 7) << 3;                  // ds_read swizzle

  for (int kt = 0; kt < K; kt += 64) {
#pragma unroll
    for (int ch = 0; ch < 4; ++ch) {
      const int rr = (ch * 4 + wid) * 8;
      gload16(A  + (long)(row0 + rr + lrow) * K + kt + lcol, sA + rr * 64);
      gload16(Bw + (long)(col0 + rr + lrow) * K + kt + lcol, sB + rr * 64);
    }
    __syncthreads();
#pragma unroll
    for (int kk = 0; kk < 2; ++kk) {
      bf16x8 af[4], bfv[4];
#pragma unroll
      for (int mi = 0; mi < 4; ++mi)
        af[mi] = *(const bf16x8*)(sA + (wr * 64 + mi * 16 + l15) * 64 + ((kk * 32 + l4 * 8) ^ ksw));
#pragma unroll
      for (int nj = 0; nj < 4; ++nj)
        bfv[nj] = *(const bf16x8*)(sB + (wc * 64 + nj * 16 + l15) * 64 + ((kk * 32 + l4 * 8) ^ ksw));
#pragma unroll
      for (int mi = 0; mi < 4; ++mi)
#pragma unroll
        for (int nj = 0; nj < 4; ++nj)
          acc[mi][nj] = __builtin_amdgcn_mfma_f32_16x16x32_bf16(af[mi], bfv[nj], acc[mi][nj], 0, 0, 0);
    }
    __syncthreads();
  }

  if (EPI == 0 && col0 >= 512) {
    // ---- v^T epilogue via per-wave LDS transpose (coalesced 16B writes) ----
    u16* tr = smem + wid * 64 * 72;   // [64 n_local][72 pad] u16
#pragma unroll
    for (int mi = 0; mi < 4; ++mi)
#pragma unroll
      for (int nj = 0; nj < 4; ++nj) {
        u16x4 p;
#pragma unroll
        for (int reg = 0; reg < 4; ++reg) p[reg] = f2b(acc[mi][nj][reg]);
        const int n_local = nj * 16 + l15;
        const int m_local = mi * 16 + (l4 << 2);
        *(u16x4*)(tr + n_local * 72 + m_local) = p;
      }
    const int rrg = (row0 >> 6) + wr;       // global window-row index (m>>6)
#pragma unroll
    for (int pass = 0; pass < 8; ++pass) {
      const int t = pass * 8 + (lane >> 3);     // n_local
      const int n = col0 + wc * 64 + t;
      const int h = (n >> 5) & 7, d = n & 31;
      const long obase = 102760448L + (long)((rrg * 8 + h) * 32 + d) * 64L;
      u16x8 vv = *(const u16x8*)(tr + t * 72 + ((lane & 7) << 3));
      *(u16x8*)(bout + obase + ((lane & 7) << 3)) = vv;
    }
    return;
  }

#pragma unroll
  for (int mi = 0; mi < 4; ++mi)
#pragma unroll
    for (int nj = 0; nj < 4; ++nj)
#pragma unroll
      for (int reg = 0; reg < 4; ++reg) {
        const int m = row0 + wr * 64 + mi * 16 + (l4 << 2) + reg;
        const int n = col0 + wc * 64 + nj * 16 + l15;
        const float v = acc[mi][nj][reg];
        if (EPI == 0) {
          const int rr = m >> 6, ii = m & 63;
          const int s = n >> 8, hh = (n >> 5) & 7, d = n & 31;
          const long idx = (long)s * 51380224L + (long)((rr * 8 + hh) * 64 + ii) * 32 + d;
          bout[idx] = f2b(v);
        } else if (EPI == 1 || EPI == 3) {
          float* yp = fout + (long)m * 256 + n;
          *yp = *yp + v + bias[n];
        } else if (EPI == 2) {
          float g = v + bias[n];
          g = 0.5f * g * (1.0f + erff(g * 0.70710678118654752f));
          bout[(long)m * 1024 + n] = f2b(g);
        }
      }
}

// ---------- per-window attention ----------
__global__ __launch_bounds__(256)
void attn_win(const u16* __restrict__ qkv, const float* __restrict__ rpb,
              u16* __restrict__ aout) {
  __shared__ float Pls[4][64 * 66];
  __shared__ float srpb[1800];
  const int tid = threadIdx.x, lane = tid & 63, wv = tid >> 6;
  const int r = blockIdx.x;
  for (int i = tid; i < 1800; i += 256) srpb[i] = rpb[i];
  __syncthreads();

  // reference quirk: jnp.repeat(mask, B, axis=0) -> window r uses mask[r/4]
  const int midx = r >> 2;
  const int wh = midx / 28, ww = midx % 28;
  const int l15 = lane & 15, l4 = lane >> 4;

  float* Pw = &Pls[wv][0];
  const u16* kb = qkv + 51380224;
  const u16* vb = qkv + 102760448;

  int rj[4], cj[4], labj[4];
#pragma unroll
  for (int nj = 0; nj < 4; ++nj) {
    const int j = nj * 16 + l15;
    rj[nj] = j >> 3; cj[nj] = j & 7;
    const int hp = wh * 8 + rj[nj], wp = ww * 8 + cj[nj];
    const int lh = (hp < 216) ? 0 : ((hp < 220) ? 1 : 2);
    const int lw = (wp < 216) ? 0 : ((wp < 220) ? 1 : 2);
    labj[nj] = lh * 3 + lw;
  }

  const f32x4 vzero = {0.f, 0.f, 0.f, 0.f};
  for (int hh = 0; hh < 2; ++hh) {
    const int h = wv * 2 + hh;
    const long hb = (long)(r * 8 + h) * 2048;
    const u16* qh = qkv + hb;
    const u16* kh = kb + hb;
    const u16* vh = vb + hb;

    bf16x8 qf[4], kf[4];
#pragma unroll
    for (int mi = 0; mi < 4; ++mi)
      qf[mi] = *(const bf16x8*)(qh + (mi * 16 + l15) * 32 + l4 * 8);
#pragma unroll
    for (int nj = 0; nj < 4; ++nj)
      kf[nj] = *(const bf16x8*)(kh + (nj * 16 + l15) * 32 + l4 * 8);

    f32x4 S[4][4];
#pragma unroll
    for (int mi = 0; mi < 4; ++mi)
#pragma unroll
      for (int nj = 0; nj < 4; ++nj)
        S[mi][nj] = __builtin_amdgcn_mfma_f32_16x16x32_bf16(qf[mi], kf[nj], vzero, 0, 0, 0);

    float rsave[4][4];
#pragma unroll
    for (int mi = 0; mi < 4; ++mi)
#pragma unroll
      for (int reg = 0; reg < 4; ++reg) {
        const int i = mi * 16 + (l4 << 2) + reg;
        const int ri = i >> 3, ci = i & 7;
        const int hp = wh * 8 + ri, wp = ww * 8 + ci;
        const int lh = (hp < 216) ? 0 : ((hp < 220) ? 1 : 2);
        const int lw = (wp < 216) ? 0 : ((wp < 220) ? 1 : 2);
        const int li = lh * 3 + lw;
        float v[4];
#pragma unroll
        for (int nj = 0; nj < 4; ++nj) {
          const int idx = (ri - rj[nj] + 7) * 15 + (ci - cj[nj] + 7);
          v[nj] = S[mi][nj][reg] * 0.17677669529663687f + srpb[idx * 8 + h]
                + ((li != labj[nj]) ? -100.0f : 0.0f);
        }
        float mx = fmaxf(fmaxf(v[0], v[1]), fmaxf(v[2], v[3]));
        mx = fmaxf(mx, __shfl_xor(mx, 1));
        mx = fmaxf(mx, __shfl_xor(mx, 2));
        mx = fmaxf(mx, __shfl_xor(mx, 4));
        mx = fmaxf(mx, __shfl_xor(mx, 8));
        float sum = 0.f;
#pragma unroll
        for (int nj = 0; nj < 4; ++nj) { v[nj] = __expf(v[nj] - mx); sum += v[nj]; }
        sum += __shfl_xor(sum, 1);
        sum += __shfl_xor(sum, 2);
        sum += __shfl_xor(sum, 4);
        sum += __shfl_xor(sum, 8);
        rsave[mi][reg] = 1.0f / sum;          // deferred normalization
#pragma unroll
        for (int nj = 0; nj < 4; ++nj) Pw[i * 66 + nj * 16 + l15] = v[nj];
      }

    f32x4 O[4][2];
#pragma unroll
    for (int mi = 0; mi < 4; ++mi) { O[mi][0] = vzero; O[mi][1] = vzero; }
#pragma unroll
    for (int kk = 0; kk < 2; ++kk) {
      bf16x8 pf[4], vf[2];
#pragma unroll
      for (int mi = 0; mi < 4; ++mi) {
        const int base = (mi * 16 + l15) * 66 + kk * 32 + l4 * 8;
        bf16x8 t;
#pragma unroll
        for (int e = 0; e < 8; ++e) t[e] = (__bf16)Pw[base + e];
        pf[mi] = t;
      }
#pragma unroll
      for (int nd = 0; nd < 2; ++nd)
        vf[nd] = *(const bf16x8*)(vh + (nd * 16 + l15) * 64 + kk * 32 + l4 * 8);
#pragma unroll
      for (int mi = 0; mi < 4; ++mi)
#pragma unroll
        for (int nd = 0; nd < 2; ++nd)
          O[mi][nd] = __builtin_amdgcn_mfma_f32_16x16x32_bf16(pf[mi], vf[nd], O[mi][nd], 0, 0, 0);
    }

#pragma unroll
    for (int mi = 0; mi < 4; ++mi)
#pragma unroll
      for (int nd = 0; nd < 2; ++nd)
#pragma unroll
        for (int reg = 0; reg < 4; ++reg) {
          const int i = mi * 16 + (l4 << 2) + reg;
          aout[(long)(r * 64 + i) * 256 + h * 32 + nd * 16 + l15] =
              f2b(O[mi][nd][reg] * rsave[mi][reg]);
        }
  }
}

// ---------- rowwise LN2 ----------
__global__ __launch_bounds__(256)
void ln2_rows(const float* __restrict__ y, const float* __restrict__ w,
              const float* __restrict__ bb, u16* __restrict__ out) {
  const int lane = threadIdx.x & 63;
  const long row = (long)blockIdx.x * 4 + (threadIdx.x >> 6);
  const float4 v = *(const float4*)(y + row * 256 + lane * 4);
  float s = v.x + v.y + v.z + v.w;
  float q = v.x * v.x + v.y * v.y + v.z * v.z + v.w * v.w;
#pragma unroll
  for (int d = 1; d < 64; d <<= 1) { s += __shfl_xor(s, d); q += __shfl_xor(q, d); }
  const float mean = s * (1.f / 256.f);
  const float rstd = rsqrtf(q * (1.f / 256.f) - mean * mean + 1e-5f);
  const int c = lane * 4;
  u16x4 o;
  o[0] = f2b((v.x - mean) * rstd * w[c + 0] + bb[c + 0]);
  o[1] = f2b((v.y - mean) * rstd * w[c + 1] + bb[c + 1]);
  o[2] = f2b((v.z - mean) * rstd * w[c + 2] + bb[c + 2]);
  o[3] = f2b((v.w - mean) * rstd * w[c + 3] + bb[c + 3]);
  *(u16x4*)(out + row * 256 + c) = o;
}

// ---------- un-window scatter ----------
__global__ __launch_bounds__(256)
void unwin(const float* __restrict__ y, float* __restrict__ out) {
  __shared__ float t[256 * 65];
  const int tid = threadIdx.x, lane = tid & 63, wv = tid >> 6;
  const int r = blockIdx.x;
  const int b = r / 784, mm = r % 784;
  const int wh = mm / 28, ww = mm % 28;
  const long base = (long)r * 64 * 256;
#pragma unroll 8
  for (int n = 0; n < 64; ++n)
    t[tid * 65 + n] = y[base + n * 256 + tid];
  __syncthreads();
  int hp = wh * 8 + (lane >> 3) + 4; if (hp >= 224) hp -= 224;
  int wp = ww * 8 + (lane & 7) + 4;  if (wp >= 224) wp -= 224;
  const int off = hp * 224 + wp;
  float* ob = out + (long)b * 256 * 50176;
#pragma unroll 8
  for (int i = 0; i < 64; ++i) {
    const int c = i * 4 + wv;
    ob[(long)c * 50176 + off] = t[c * 65 + lane];
  }
}

// ---------- launch ----------
extern "C" void kernel_launch(void* const* d_in, const int* in_sizes, int n_in,
                              void* d_out, int out_size, void* d_ws, size_t ws_size,
                              hipStream_t stream) {
  (void)in_sizes; (void)n_in; (void)out_size; (void)ws_size;
  const float* x     = (const float*)d_in[0];
  const float* qkvw  = (const float*)d_in[1];
  const float* projw = (const float*)d_in[2];
  const float* projb = (const float*)d_in[3];
  const float* rpb   = (const float*)d_in[4];
  const float* n1w   = (const float*)d_in[5];
  const float* n1b   = (const float*)d_in[6];
  const float* n2w   = (const float*)d_in[7];
  const float* n2b   = (const float*)d_in[8];
  const float* w1    = (const float*)d_in[9];
  const float* b1    = (const float*)d_in[10];
  const float* w2    = (const float*)d_in[11];
  const float* b2    = (const float*)d_in[12];

  char* ws = (char*)d_ws;
  u16*   hbuf   = (u16*)(ws);                  // 102,760,448 B : h, later h2
  u16*   qkvb   = (u16*)(ws + 102760448);      // 308,281,344 B : q|k|v
  u16*   abuf   = (u16*)(ws + 411041792);      // 102,760,448 B : attn out
  float* ybuf   = (float*)(ws + 513802240);    // 205,520,896 B : fp32 residual stream
  u16*   hidb   = (u16*)(ws + 102760448);      // 411,041,792 B : overlays qkv+attn (dead by then)
  u16*   qkvwb  = (u16*)(ws + 719323136);
  u16*   projwb = (u16*)(ws + 719716352);
  u16*   w1b    = (u16*)(ws + 719847424);
  u16*   w2b    = (u16*)(ws + 720371712);      // end: 720,896,000 B

  conv_weights<<<3072, 256, 0, stream>>>(qkvw, projw, w1, w2, qkvwb, projwb, w1b, w2b);
  ln1_win<<<3136, 256, 0, stream>>>(x, n1w, n1b, hbuf, ybuf);
  gemm_bt<0, 6><<<9408, 256, 0, stream>>>(hbuf, qkvwb, 256, nullptr, nullptr, qkvb);
  attn_win<<<3136, 256, 0, stream>>>(qkvb, rpb, abuf);
  gemm_bt<1, 2><<<3136, 256, 0, stream>>>(abuf, projwb, 256, ybuf, projb, nullptr);
  ln2_rows<<<50176, 256, 0, stream>>>(ybuf, n2w, n2b, hbuf);
  gemm_bt<2, 8><<<12544, 256, 0, stream>>>(hbuf, w1b, 256, nullptr, b1, hidb);
  gemm_bt<3, 2><<<3136, 256, 0, stream>>>(hidb, w2b, 1024, ybuf, b2, nullptr);
  unwin<<<3136, 256, 0, stream>>>(ybuf, (float*)d_out);
}

// Round 3
// 1468.544 us; speedup vs baseline: 1.1919x; 1.0631x over previous
//
#include <hip/hip_runtime.h>

typedef unsigned short u16;
typedef unsigned int   u32;
typedef __attribute__((ext_vector_type(8))) __bf16 bf16x8;
typedef __attribute__((ext_vector_type(4))) float  f32x4;
typedef __attribute__((ext_vector_type(4))) u16    u16x4;
typedef __attribute__((ext_vector_type(8))) u16    u16x8;

#define DEV __device__ __forceinline__

// ---------- helpers ----------
DEV u16 f2b(float f) {               // fp32 -> bf16 bits, RNE
  union { float f; u32 u; } a; a.f = f;
  const u32 u = a.u;
  return (u16)((u + 0x7fffu + ((u >> 16) & 1u)) >> 16);
}

// tanh-form GELU as x*sigmoid(1.5957691*(x+0.044715 x^3)); exp2-folded.
// max |diff| vs exact erf-GELU ~3e-4. Overflow-safe: z->+inf => r->0 => x.
DEV float gelu_fast(float x) {
  const float x2 = x * x;
  const float t  = __builtin_fmaf(0.1029430f, x2, 2.3022150f);  // *log2(e) folded
  const float e  = __builtin_exp2f(x * t);
  const float r  = __builtin_amdgcn_rcpf(1.0f + e);
  return __builtin_fmaf(-x, r, x);   // x - x/(1+e) = x*sigmoid(z)
}

DEV void gload16(const void* g, void* l) {
  __builtin_amdgcn_global_load_lds(
      (const __attribute__((address_space(1))) void*)g,
      (__attribute__((address_space(3))) void*)l, 16, 0, 0);
}

// ---------- weight conversion (fp32 -> bf16) ----------
__global__ __launch_bounds__(256)
void conv_weights(const float* __restrict__ qkvw, const float* __restrict__ projw,
                  const float* __restrict__ w1,   const float* __restrict__ w2,
                  u16* __restrict__ dq, u16* __restrict__ dp,
                  u16* __restrict__ d1, u16* __restrict__ d2) {
  const int t = blockIdx.x * 256 + threadIdx.x;
  if (t < 196608)      dq[t]          = f2b(qkvw[t]);
  else if (t < 262144) dp[t - 196608] = f2b(projw[t - 196608]);
  else if (t < 524288) d1[t - 262144] = f2b(w1[t - 262144]);
  else                 d2[t - 524288] = f2b(w2[t - 524288]);
}

// ---------- window gather + LN1, 4 adjacent windows per block ----------
// Block g: windows base_r..base_r+3 (same wh, ww = wg*4..+3) => 8 image rows x
// 32 consecutive columns. Thread tid owns pixel p=tid (pr=tid>>5, pc=tid&31).
// Pass1: read x (128B segments), accumulate LN sums in regs, LDS-transpose,
//        write xw [m][c] coalesced.
// Pass2: re-read xw (L2-hot), apply LN, write h bf16 coalesced.
__global__ __launch_bounds__(256)
void ln1_win(const float* __restrict__ x, const float* __restrict__ w1,
             const float* __restrict__ b1, u16* __restrict__ hout,
             float* __restrict__ xwout) {
  __shared__ float xt[64 * 257];
  __shared__ float smean[256], srstd[256];
  const int tid = threadIdx.x, lane = tid & 63, wv = tid >> 6;
  const int g = blockIdx.x;
  const int b = g / 196, rem = g % 196;
  const int wh = rem / 7, wg = rem % 7;
  const int base_r = b * 784 + wh * 28 + wg * 4;
  const int pr = tid >> 5, pc = tid & 31;
  int hp = wh * 8 + 4 + pr; if (hp >= 224) hp -= 224;
  int wp = wg * 32 + 4 + pc; if (wp >= 224) wp -= 224;
  const long roff = (long)b * 256 * 50176 + hp * 224 + wp;

  float s = 0.f, q = 0.f;
  for (int cc = 0; cc < 4; ++cc) {
#pragma unroll 8
    for (int i = 0; i < 64; ++i) {
      const int c = cc * 64 + i;
      const float v = x[(long)c * 50176 + roff];
      xt[i * 257 + tid] = v;
      s += v; q += v * v;
    }
    __syncthreads();
#pragma unroll 8
    for (int jj = 0; jj < 64; ++jj) {
      const int p = jj * 4 + wv;
      const int m = (base_r + ((p & 31) >> 3)) * 64 + (p >> 5) * 8 + (p & 7);
      xwout[(long)m * 256 + cc * 64 + lane] = xt[lane * 257 + p];
    }
    __syncthreads();
  }
  const float mean = s * (1.f / 256.f);
  smean[tid] = mean;
  srstd[tid] = rsqrtf(q * (1.f / 256.f) - mean * mean + 1e-5f);
  __syncthreads();

  float wr_[4], br_[4];
#pragma unroll
  for (int cc = 0; cc < 4; ++cc) { wr_[cc] = w1[cc * 64 + lane]; br_[cc] = b1[cc * 64 + lane]; }
#pragma unroll 2
  for (int jj = 0; jj < 64; ++jj) {
    const int p = jj * 4 + wv;
    const int m = (base_r + ((p & 31) >> 3)) * 64 + (p >> 5) * 8 + (p & 7);
    const float mu = smean[p], rs = srstd[p];
#pragma unroll
    for (int cc = 0; cc < 4; ++cc) {
      const float v = xwout[(long)m * 256 + cc * 64 + lane];
      hout[(long)m * 256 + cc * 64 + lane] = f2b((v - mu) * rs * wr_[cc] + br_[cc]);
    }
  }
}

// ---------- generic 128x128x(BK=64) bf16 GEMM, B given as [N][K] ----------
// 1-D grid, XCD-chunk swizzle + column-fast decode (A-tile L2 reuse).
// LDS k-slot XOR swizzle (T2).
// EPI 0: qkv scatter (q | k | v^T); v^T via per-wave LDS transpose
// EPI 1/3: y[m][n] += acc + bias[n]
// EPI 2: hidden[m][n] = bf16(gelu_fast(acc+b)), ldc=1024
template<int EPI, int NCOL>
__global__ __launch_bounds__(256)
void gemm_bt(const u16* __restrict__ A, const u16* __restrict__ Bw, const int K,
             float* __restrict__ fout, const float* __restrict__ bias,
             u16* __restrict__ bout) {
  __shared__ __align__(16) u16 smem[(EPI == 0) ? (4 * 64 * 72) : (2 * 128 * 64)];
  u16* sA = smem;
  u16* sB = smem + 128 * 64;

  const int tid  = threadIdx.x;
  const int lane = tid & 63;
  const int wid  = tid >> 6;
  const int wr   = wid >> 1;
  const int wc   = wid & 1;

  const int nwg = gridDim.x;
  const int bid = blockIdx.x;
  const int wg  = (bid & 7) * (nwg >> 3) + (bid >> 3);   // XCD chunk swizzle
  const int row_blk = wg / NCOL;                          // column-fast
  const int col_blk = wg - row_blk * NCOL;
  const int row0 = row_blk * 128;
  const int col0 = col_blk * 128;

  const f32x4 vzero = {0.f, 0.f, 0.f, 0.f};
  f32x4 acc[4][4];
#pragma unroll
  for (int i = 0; i < 4; ++i)
#pragma unroll
    for (int j = 0; j < 4; ++j) acc[i][j] = vzero;

  const int lrow = lane >> 3;
  const int lcol = ((lane & 7) << 3) ^ (lane & 56);  // pre-swizzled source k-offset
  const int l15  = lane & 15;
  const int l4   = lane >> 4;
  const int ksw  = (lane & 7) << 3;                  // ds_read swizzle

  for (int kt = 0; kt < K; kt += 64) {
#pragma unroll
    for (int ch = 0; ch < 4; ++ch) {
      const int rr = (ch * 4 + wid) * 8;
      gload16(A  + (long)(row0 + rr + lrow) * K + kt + lcol, sA + rr * 64);
      gload16(Bw + (long)(col0 + rr + lrow) * K + kt + lcol, sB + rr * 64);
    }
    __syncthreads();
#pragma unroll
    for (int kk = 0; kk < 2; ++kk) {
      bf16x8 af[4], bfv[4];
#pragma unroll
      for (int mi = 0; mi < 4; ++mi)
        af[mi] = *(const bf16x8*)(sA + (wr * 64 + mi * 16 + l15) * 64 + ((kk * 32 + l4 * 8) ^ ksw));
#pragma unroll
      for (int nj = 0; nj < 4; ++nj)
        bfv[nj] = *(const bf16x8*)(sB + (wc * 64 + nj * 16 + l15) * 64 + ((kk * 32 + l4 * 8) ^ ksw));
#pragma unroll
      for (int mi = 0; mi < 4; ++mi)
#pragma unroll
        for (int nj = 0; nj < 4; ++nj)
          acc[mi][nj] = __builtin_amdgcn_mfma_f32_16x16x32_bf16(af[mi], bfv[nj], acc[mi][nj], 0, 0, 0);
    }
    __syncthreads();
  }

  if (EPI == 0 && col0 >= 512) {
    // ---- v^T epilogue via per-wave LDS transpose (coalesced 16B writes) ----
    u16* tr = smem + wid * 64 * 72;   // [64 n_local][72 pad] u16
#pragma unroll
    for (int mi = 0; mi < 4; ++mi)
#pragma unroll
      for (int nj = 0; nj < 4; ++nj) {
        u16x4 p;
#pragma unroll
        for (int reg = 0; reg < 4; ++reg) p[reg] = f2b(acc[mi][nj][reg]);
        const int n_local = nj * 16 + l15;
        const int m_local = mi * 16 + (l4 << 2);
        *(u16x4*)(tr + n_local * 72 + m_local) = p;
      }
    const int rrg = (row0 >> 6) + wr;       // global window-row index (m>>6)
#pragma unroll
    for (int pass = 0; pass < 8; ++pass) {
      const int t = pass * 8 + (lane >> 3);     // n_local
      const int n = col0 + wc * 64 + t;
      const int h = (n >> 5) & 7, d = n & 31;
      const long obase = 102760448L + (long)((rrg * 8 + h) * 32 + d) * 64L;
      u16x8 vv = *(const u16x8*)(tr + t * 72 + ((lane & 7) << 3));
      *(u16x8*)(bout + obase + ((lane & 7) << 3)) = vv;
    }
    return;
  }

  float bias_r[4];
  if (EPI != 0) {
#pragma unroll
    for (int nj = 0; nj < 4; ++nj)
      bias_r[nj] = bias[col0 + wc * 64 + nj * 16 + l15];
  }

#pragma unroll
  for (int mi = 0; mi < 4; ++mi)
#pragma unroll
    for (int nj = 0; nj < 4; ++nj)
#pragma unroll
      for (int reg = 0; reg < 4; ++reg) {
        const int m = row0 + wr * 64 + mi * 16 + (l4 << 2) + reg;
        const int n = col0 + wc * 64 + nj * 16 + l15;
        const float v = acc[mi][nj][reg];
        if (EPI == 0) {
          const int rr = m >> 6, ii = m & 63;
          const int s = n >> 8, hh = (n >> 5) & 7, d = n & 31;
          const long idx = (long)s * 51380224L + (long)((rr * 8 + hh) * 64 + ii) * 32 + d;
          bout[idx] = f2b(v);
        } else if (EPI == 1 || EPI == 3) {
          float* yp = fout + (long)m * 256 + n;
          *yp = *yp + v + bias_r[nj];
        } else if (EPI == 2) {
          bout[(long)m * 1024 + n] = f2b(gelu_fast(v + bias_r[nj]));
        }
      }
}

// ---------- per-window attention ----------
__global__ __launch_bounds__(256)
void attn_win(const u16* __restrict__ qkv, const float* __restrict__ rpb,
              u16* __restrict__ aout) {
  __shared__ float Pls[4][64 * 66];
  __shared__ float srpb[1800];
  const int tid = threadIdx.x, lane = tid & 63, wv = tid >> 6;
  const int r = blockIdx.x;
  for (int i = tid; i < 1800; i += 256) srpb[i] = rpb[i];
  __syncthreads();

  // reference quirk: jnp.repeat(mask, B, axis=0) -> window r uses mask[r/4]
  const int midx = r >> 2;
  const int wh = midx / 28, ww = midx % 28;
  const int l15 = lane & 15, l4 = lane >> 4;

  float* Pw = &Pls[wv][0];
  const u16* kb = qkv + 51380224;
  const u16* vb = qkv + 102760448;

  int rj[4], cj[4], labj[4];
#pragma unroll
  for (int nj = 0; nj < 4; ++nj) {
    const int j = nj * 16 + l15;
    rj[nj] = j >> 3; cj[nj] = j & 7;
    const int hp = wh * 8 + rj[nj], wp = ww * 8 + cj[nj];
    const int lh = (hp < 216) ? 0 : ((hp < 220) ? 1 : 2);
    const int lw = (wp < 216) ? 0 : ((wp < 220) ? 1 : 2);
    labj[nj] = lh * 3 + lw;
  }

  const f32x4 vzero = {0.f, 0.f, 0.f, 0.f};
  for (int hh = 0; hh < 2; ++hh) {
    const int h = wv * 2 + hh;
    const long hb = (long)(r * 8 + h) * 2048;
    const u16* qh = qkv + hb;
    const u16* kh = kb + hb;
    const u16* vh = vb + hb;

    bf16x8 qf[4], kf[4];
#pragma unroll
    for (int mi = 0; mi < 4; ++mi)
      qf[mi] = *(const bf16x8*)(qh + (mi * 16 + l15) * 32 + l4 * 8);
#pragma unroll
    for (int nj = 0; nj < 4; ++nj)
      kf[nj] = *(const bf16x8*)(kh + (nj * 16 + l15) * 32 + l4 * 8);

    f32x4 S[4][4];
#pragma unroll
    for (int mi = 0; mi < 4; ++mi)
#pragma unroll
      for (int nj = 0; nj < 4; ++nj)
        S[mi][nj] = __builtin_amdgcn_mfma_f32_16x16x32_bf16(qf[mi], kf[nj], vzero, 0, 0, 0);

    float rsave[4][4];
#pragma unroll
    for (int mi = 0; mi < 4; ++mi)
#pragma unroll
      for (int reg = 0; reg < 4; ++reg) {
        const int i = mi * 16 + (l4 << 2) + reg;
        const int ri = i >> 3, ci = i & 7;
        const int hp = wh * 8 + ri, wp = ww * 8 + ci;
        const int lh = (hp < 216) ? 0 : ((hp < 220) ? 1 : 2);
        const int lw = (wp < 216) ? 0 : ((wp < 220) ? 1 : 2);
        const int li = lh * 3 + lw;
        float v[4];
#pragma unroll
        for (int nj = 0; nj < 4; ++nj) {
          const int idx = (ri - rj[nj] + 7) * 15 + (ci - cj[nj] + 7);
          v[nj] = S[mi][nj][reg] * 0.17677669529663687f + srpb[idx * 8 + h]
                + ((li != labj[nj]) ? -100.0f : 0.0f);
        }
        float mx = fmaxf(fmaxf(v[0], v[1]), fmaxf(v[2], v[3]));
        mx = fmaxf(mx, __shfl_xor(mx, 1));
        mx = fmaxf(mx, __shfl_xor(mx, 2));
        mx = fmaxf(mx, __shfl_xor(mx, 4));
        mx = fmaxf(mx, __shfl_xor(mx, 8));
        float sum = 0.f;
#pragma unroll
        for (int nj = 0; nj < 4; ++nj) { v[nj] = __expf(v[nj] - mx); sum += v[nj]; }
        sum += __shfl_xor(sum, 1);
        sum += __shfl_xor(sum, 2);
        sum += __shfl_xor(sum, 4);
        sum += __shfl_xor(sum, 8);
        rsave[mi][reg] = 1.0f / sum;          // deferred normalization
#pragma unroll
        for (int nj = 0; nj < 4; ++nj) Pw[i * 66 + nj * 16 + l15] = v[nj];
      }

    f32x4 O[4][2];
#pragma unroll
    for (int mi = 0; mi < 4; ++mi) { O[mi][0] = vzero; O[mi][1] = vzero; }
#pragma unroll
    for (int kk = 0; kk < 2; ++kk) {
      bf16x8 pf[4], vf[2];
#pragma unroll
      for (int mi = 0; mi < 4; ++mi) {
        const int base = (mi * 16 + l15) * 66 + kk * 32 + l4 * 8;
        bf16x8 t;
#pragma unroll
        for (int e = 0; e < 8; ++e) t[e] = (__bf16)Pw[base + e];
        pf[mi] = t;
      }
#pragma unroll
      for (int nd = 0; nd < 2; ++nd)
        vf[nd] = *(const bf16x8*)(vh + (nd * 16 + l15) * 64 + kk * 32 + l4 * 8);
#pragma unroll
      for (int mi = 0; mi < 4; ++mi)
#pragma unroll
        for (int nd = 0; nd < 2; ++nd)
          O[mi][nd] = __builtin_amdgcn_mfma_f32_16x16x32_bf16(pf[mi], vf[nd], O[mi][nd], 0, 0, 0);
    }

#pragma unroll
    for (int mi = 0; mi < 4; ++mi)
#pragma unroll
      for (int nd = 0; nd < 2; ++nd)
#pragma unroll
        for (int reg = 0; reg < 4; ++reg) {
          const int i = mi * 16 + (l4 << 2) + reg;
          aout[(long)(r * 64 + i) * 256 + h * 32 + nd * 16 + l15] =
              f2b(O[mi][nd][reg] * rsave[mi][reg]);
        }
  }
}

// ---------- rowwise LN2 ----------
__global__ __launch_bounds__(256)
void ln2_rows(const float* __restrict__ y, const float* __restrict__ w,
              const float* __restrict__ bb, u16* __restrict__ out) {
  const int lane = threadIdx.x & 63;
  const long row = (long)blockIdx.x * 4 + (threadIdx.x >> 6);
  const float4 v = *(const float4*)(y + row * 256 + lane * 4);
  float s = v.x + v.y + v.z + v.w;
  float q = v.x * v.x + v.y * v.y + v.z * v.z + v.w * v.w;
#pragma unroll
  for (int d = 1; d < 64; d <<= 1) { s += __shfl_xor(s, d); q += __shfl_xor(q, d); }
  const float mean = s * (1.f / 256.f);
  const float rstd = rsqrtf(q * (1.f / 256.f) - mean * mean + 1e-5f);
  const int c = lane * 4;
  u16x4 o;
  o[0] = f2b((v.x - mean) * rstd * w[c + 0] + bb[c + 0]);
  o[1] = f2b((v.y - mean) * rstd * w[c + 1] + bb[c + 1]);
  o[2] = f2b((v.z - mean) * rstd * w[c + 2] + bb[c + 2]);
  o[3] = f2b((v.w - mean) * rstd * w[c + 3] + bb[c + 3]);
  *(u16x4*)(out + row * 256 + c) = o;
}

// ---------- un-window scatter, 4 adjacent windows per block ----------
__global__ __launch_bounds__(256)
void unwin(const float* __restrict__ y, float* __restrict__ out) {
  __shared__ float xt[64 * 257];
  const int tid = threadIdx.x, lane = tid & 63, wv = tid >> 6;
  const int g = blockIdx.x;
  const int b = g / 196, rem = g % 196;
  const int wh = rem / 7, wg = rem % 7;
  const int base_r = b * 784 + wh * 28 + wg * 4;
  const int pr = tid >> 5, pc = tid & 31;
  int hp = wh * 8 + 4 + pr; if (hp >= 224) hp -= 224;
  int wp = wg * 32 + 4 + pc; if (wp >= 224) wp -= 224;
  const long woff = (long)b * 256 * 50176 + hp * 224 + wp;

  for (int cc = 0; cc < 4; ++cc) {
#pragma unroll 8
    for (int jj = 0; jj < 64; ++jj) {
      const int p = jj * 4 + wv;
      const int m = (base_r + ((p & 31) >> 3)) * 64 + (p >> 5) * 8 + (p & 7);
      xt[lane * 257 + p] = y[(long)m * 256 + cc * 64 + lane];
    }
    __syncthreads();
#pragma unroll 8
    for (int i = 0; i < 64; ++i)
      out[(long)(cc * 64 + i) * 50176 + woff] = xt[i * 257 + tid];
    __syncthreads();
  }
}

// ---------- launch ----------
extern "C" void kernel_launch(void* const* d_in, const int* in_sizes, int n_in,
                              void* d_out, int out_size, void* d_ws, size_t ws_size,
                              hipStream_t stream) {
  (void)in_sizes; (void)n_in; (void)out_size; (void)ws_size;
  const float* x     = (const float*)d_in[0];
  const float* qkvw  = (const float*)d_in[1];
  const float* projw = (const float*)d_in[2];
  const float* projb = (const float*)d_in[3];
  const float* rpb   = (const float*)d_in[4];
  const float* n1w   = (const float*)d_in[5];
  const float* n1b   = (const float*)d_in[6];
  const float* n2w   = (const float*)d_in[7];
  const float* n2b   = (const float*)d_in[8];
  const float* w1    = (const float*)d_in[9];
  const float* b1    = (const float*)d_in[10];
  const float* w2    = (const float*)d_in[11];
  const float* b2    = (const float*)d_in[12];

  char* ws = (char*)d_ws;
  u16*   hbuf   = (u16*)(ws);                  // 102,760,448 B : h, later h2
  u16*   qkvb   = (u16*)(ws + 102760448);      // 308,281,344 B : q|k|v
  u16*   abuf   = (u16*)(ws + 411041792);      // 102,760,448 B : attn out
  float* ybuf   = (float*)(ws + 513802240);    // 205,520,896 B : fp32 residual stream
  u16*   hidb   = (u16*)(ws + 102760448);      // 411,041,792 B : overlays qkv+attn (dead by then)
  u16*   qkvwb  = (u16*)(ws + 719323136);
  u16*   projwb = (u16*)(ws + 719716352);
  u16*   w1b    = (u16*)(ws + 719847424);
  u16*   w2b    = (u16*)(ws + 720371712);      // end: 720,896,000 B

  conv_weights<<<3072, 256, 0, stream>>>(qkvw, projw, w1, w2, qkvwb, projwb, w1b, w2b);
  ln1_win<<<784, 256, 0, stream>>>(x, n1w, n1b, hbuf, ybuf);
  gemm_bt<0, 6><<<9408, 256, 0, stream>>>(hbuf, qkvwb, 256, nullptr, nullptr, qkvb);
  attn_win<<<3136, 256, 0, stream>>>(qkvb, rpb, abuf);
  gemm_bt<1, 2><<<3136, 256, 0, stream>>>(abuf, projwb, 256, ybuf, projb, nullptr);
  ln2_rows<<<50176, 256, 0, stream>>>(ybuf, n2w, n2b, hbuf);
  gemm_bt<2, 8><<<12544, 256, 0, stream>>>(hbuf, w1b, 256, nullptr, b1, hidb);
  gemm_bt<3, 2><<<3136, 256, 0, stream>>>(hidb, w2b, 1024, ybuf, b2, nullptr);
  unwin<<<784, 256, 0, stream>>>(ybuf, (float*)d_out);
}

// Round 4
// 1443.097 us; speedup vs baseline: 1.2129x; 1.0176x over previous
//
#include <hip/hip_runtime.h>

typedef unsigned short u16;
typedef unsigned int   u32;
typedef __attribute__((ext_vector_type(8))) __bf16 bf16x8;
typedef __attribute__((ext_vector_type(4))) float  f32x4;
typedef __attribute__((ext_vector_type(4))) u16    u16x4;
typedef __attribute__((ext_vector_type(8))) u16    u16x8;

#define DEV __device__ __forceinline__

// ---------- helpers ----------
DEV u16 f2b(float f) {               // fp32 -> bf16 bits, RNE
  union { float f; u32 u; } a; a.f = f;
  const u32 u = a.u;
  return (u16)((u + 0x7fffu + ((u >> 16) & 1u)) >> 16);
}

// tanh-form GELU as x*sigmoid(1.5957691*(x+0.044715 x^3)); exp2-folded.
// max |diff| vs exact erf-GELU ~3e-4. Overflow-safe: z->+inf => r->0 => x.
DEV float gelu_fast(float x) {
  const float x2 = x * x;
  const float t  = __builtin_fmaf(0.1029430f, x2, 2.3022150f);  // *log2(e) folded
  const float e  = __builtin_exp2f(x * t);
  const float r  = __builtin_amdgcn_rcpf(1.0f + e);
  return __builtin_fmaf(-x, r, x);   // x - x/(1+e) = x*sigmoid(z)
}

DEV void gload16(const void* g, void* l) {
  __builtin_amdgcn_global_load_lds(
      (const __attribute__((address_space(1))) void*)g,
      (__attribute__((address_space(3))) void*)l, 16, 0, 0);
}

// ---------- weight conversion (fp32 -> bf16) ----------
__global__ __launch_bounds__(256)
void conv_weights(const float* __restrict__ qkvw, const float* __restrict__ projw,
                  const float* __restrict__ w1,   const float* __restrict__ w2,
                  u16* __restrict__ dq, u16* __restrict__ dp,
                  u16* __restrict__ d1, u16* __restrict__ d2) {
  const int t = blockIdx.x * 256 + threadIdx.x;
  if (t < 196608)      dq[t]          = f2b(qkvw[t]);
  else if (t < 262144) dp[t - 196608] = f2b(projw[t - 196608]);
  else if (t < 524288) d1[t - 262144] = f2b(w1[t - 262144]);
  else                 d2[t - 524288] = f2b(w2[t - 524288]);
}

// ---------- window gather + LN1, 4 adjacent windows per block ----------
__global__ __launch_bounds__(256)
void ln1_win(const float* __restrict__ x, const float* __restrict__ w1,
             const float* __restrict__ b1, u16* __restrict__ hout,
             float* __restrict__ xwout) {
  __shared__ float xt[64 * 257];
  __shared__ float smean[256], srstd[256];
  const int tid = threadIdx.x, lane = tid & 63, wv = tid >> 6;
  const int g = blockIdx.x;
  const int b = g / 196, rem = g % 196;
  const int wh = rem / 7, wg = rem % 7;
  const int base_r = b * 784 + wh * 28 + wg * 4;
  const int pr = tid >> 5, pc = tid & 31;
  int hp = wh * 8 + 4 + pr; if (hp >= 224) hp -= 224;
  int wp = wg * 32 + 4 + pc; if (wp >= 224) wp -= 224;
  const long roff = (long)b * 256 * 50176 + hp * 224 + wp;

  float s = 0.f, q = 0.f;
  for (int cc = 0; cc < 4; ++cc) {
#pragma unroll 8
    for (int i = 0; i < 64; ++i) {
      const int c = cc * 64 + i;
      const float v = x[(long)c * 50176 + roff];
      xt[i * 257 + tid] = v;
      s += v; q += v * v;
    }
    __syncthreads();
#pragma unroll 8
    for (int jj = 0; jj < 64; ++jj) {
      const int p = jj * 4 + wv;
      const int m = (base_r + ((p & 31) >> 3)) * 64 + (p >> 5) * 8 + (p & 7);
      xwout[(long)m * 256 + cc * 64 + lane] = xt[lane * 257 + p];
    }
    __syncthreads();
  }
  const float mean = s * (1.f / 256.f);
  smean[tid] = mean;
  srstd[tid] = rsqrtf(q * (1.f / 256.f) - mean * mean + 1e-5f);
  __syncthreads();

  float wr_[4], br_[4];
#pragma unroll
  for (int cc = 0; cc < 4; ++cc) { wr_[cc] = w1[cc * 64 + lane]; br_[cc] = b1[cc * 64 + lane]; }
#pragma unroll 2
  for (int jj = 0; jj < 64; ++jj) {
    const int p = jj * 4 + wv;
    const int m = (base_r + ((p & 31) >> 3)) * 64 + (p >> 5) * 8 + (p & 7);
    const float mu = smean[p], rs = srstd[p];
#pragma unroll
    for (int cc = 0; cc < 4; ++cc) {
      const float v = xwout[(long)m * 256 + cc * 64 + lane];
      hout[(long)m * 256 + cc * 64 + lane] = f2b((v - mu) * rs * wr_[cc] + br_[cc]);
    }
  }
}

// ---------- generic 128x128x(BK=64) bf16 GEMM, B given as [N][K] ----------
// 2-phase double-buffered staging (T3-minimum): issue next tile's
// global_load_lds BEFORE computing current tile; one vmcnt-drain barrier
// per K-step AFTER compute. 1-D grid, XCD swizzle, column-fast, T2 swizzle.
// EPI 0: qkv scatter (q | k | v^T); v^T via per-wave LDS transpose
// EPI 1/3: y[m][n] += acc + bias[n]
// EPI 2: hidden[m][n] = bf16(gelu_fast(acc+b)), ldc=1024
template<int EPI, int NCOL>
__global__ __launch_bounds__(256)
void gemm_bt(const u16* __restrict__ A, const u16* __restrict__ Bw, const int K,
             float* __restrict__ fout, const float* __restrict__ bias,
             u16* __restrict__ bout) {
  __shared__ __align__(16) u16 smem[32768];   // 64 KB: 2 x (A 128x64 + B 128x64)
  u16* sA0 = smem;
  u16* sB0 = smem + 8192;
  u16* sA1 = smem + 16384;
  u16* sB1 = smem + 24576;

  const int tid  = threadIdx.x;
  const int lane = tid & 63;
  const int wid  = tid >> 6;
  const int wr   = wid >> 1;
  const int wc   = wid & 1;

  const int nwg = gridDim.x;
  const int bid = blockIdx.x;
  const int wg  = (bid & 7) * (nwg >> 3) + (bid >> 3);   // XCD chunk swizzle
  const int row_blk = wg / NCOL;                          // column-fast
  const int col_blk = wg - row_blk * NCOL;
  const int row0 = row_blk * 128;
  const int col0 = col_blk * 128;

  const f32x4 vzero = {0.f, 0.f, 0.f, 0.f};
  f32x4 acc[4][4];
#pragma unroll
  for (int i = 0; i < 4; ++i)
#pragma unroll
    for (int j = 0; j < 4; ++j) acc[i][j] = vzero;

  const int lrow = lane >> 3;
  const int lcol = ((lane & 7) << 3) ^ (lane & 56);  // pre-swizzled source k-offset
  const int l15  = lane & 15;
  const int l4   = lane >> 4;
  const int ksw  = (lane & 7) << 3;                  // ds_read swizzle

  const u16* pA = A  + (long)(row0 + lrow) * K + lcol;
  const u16* pB = Bw + (long)(col0 + lrow) * K + lcol;

#define STAGE_TILE(KT, DA, DB)                                       \
  {                                                                  \
    _Pragma("unroll")                                                \
    for (int ch = 0; ch < 4; ++ch) {                                 \
      const int rr = (ch * 4 + wid) * 8;                             \
      gload16(pA + (long)rr * K + (KT), (DA) + rr * 64);             \
      gload16(pB + (long)rr * K + (KT), (DB) + rr * 64);             \
    }                                                                \
  }

#define COMPUTE_TILE(SA, SB)                                                            \
  {                                                                                     \
    _Pragma("unroll")                                                                   \
    for (int kk = 0; kk < 2; ++kk) {                                                    \
      bf16x8 af[4], bfv[4];                                                             \
      _Pragma("unroll")                                                                 \
      for (int mi = 0; mi < 4; ++mi)                                                    \
        af[mi] = *(const bf16x8*)((SA) + (wr * 64 + mi * 16 + l15) * 64 +               \
                                  ((kk * 32 + l4 * 8) ^ ksw));                          \
      _Pragma("unroll")                                                                 \
      for (int nj = 0; nj < 4; ++nj)                                                    \
        bfv[nj] = *(const bf16x8*)((SB) + (wc * 64 + nj * 16 + l15) * 64 +              \
                                   ((kk * 32 + l4 * 8) ^ ksw));                         \
      _Pragma("unroll")                                                                 \
      for (int mi = 0; mi < 4; ++mi)                                                    \
        _Pragma("unroll")                                                               \
        for (int nj = 0; nj < 4; ++nj)                                                  \
          acc[mi][nj] = __builtin_amdgcn_mfma_f32_16x16x32_bf16(af[mi], bfv[nj],        \
                                                                acc[mi][nj], 0, 0, 0); \
    }                                                                                   \
  }

  const int nt = K >> 6;
  STAGE_TILE(0, sA0, sB0);
  __syncthreads();
  for (int t = 0; t < nt; t += 2) {
    if (t + 1 < nt) STAGE_TILE((t + 1) << 6, sA1, sB1);
    COMPUTE_TILE(sA0, sB0);
    __syncthreads();
    if (t + 1 < nt) {
      if (t + 2 < nt) STAGE_TILE((t + 2) << 6, sA0, sB0);
      COMPUTE_TILE(sA1, sB1);
      __syncthreads();
    }
  }
#undef STAGE_TILE
#undef COMPUTE_TILE

  if (EPI == 0 && col0 >= 512) {
    // ---- v^T epilogue via per-wave LDS transpose (coalesced 16B writes) ----
    u16* tr = smem + wid * 64 * 72;   // [64 n_local][72 pad] u16
#pragma unroll
    for (int mi = 0; mi < 4; ++mi)
#pragma unroll
      for (int nj = 0; nj < 4; ++nj) {
        u16x4 p;
#pragma unroll
        for (int reg = 0; reg < 4; ++reg) p[reg] = f2b(acc[mi][nj][reg]);
        const int n_local = nj * 16 + l15;
        const int m_local = mi * 16 + (l4 << 2);
        *(u16x4*)(tr + n_local * 72 + m_local) = p;
      }
    const int rrg = (row0 >> 6) + wr;       // global window-row index (m>>6)
#pragma unroll
    for (int pass = 0; pass < 8; ++pass) {
      const int t = pass * 8 + (lane >> 3);     // n_local
      const int n = col0 + wc * 64 + t;
      const int h = (n >> 5) & 7, d = n & 31;
      const long obase = 102760448L + (long)((rrg * 8 + h) * 32 + d) * 64L;
      u16x8 vv = *(const u16x8*)(tr + t * 72 + ((lane & 7) << 3));
      *(u16x8*)(bout + obase + ((lane & 7) << 3)) = vv;
    }
    return;
  }

  float bias_r[4];
  if (EPI != 0) {
#pragma unroll
    for (int nj = 0; nj < 4; ++nj)
      bias_r[nj] = bias[col0 + wc * 64 + nj * 16 + l15];
  }

#pragma unroll
  for (int mi = 0; mi < 4; ++mi)
#pragma unroll
    for (int nj = 0; nj < 4; ++nj)
#pragma unroll
      for (int reg = 0; reg < 4; ++reg) {
        const int m = row0 + wr * 64 + mi * 16 + (l4 << 2) + reg;
        const int n = col0 + wc * 64 + nj * 16 + l15;
        const float v = acc[mi][nj][reg];
        if (EPI == 0) {
          const int rr = m >> 6, ii = m & 63;
          const int s = n >> 8, hh = (n >> 5) & 7, d = n & 31;
          const long idx = (long)s * 51380224L + (long)((rr * 8 + hh) * 64 + ii) * 32 + d;
          bout[idx] = f2b(v);
        } else if (EPI == 1 || EPI == 3) {
          float* yp = fout + (long)m * 256 + n;
          *yp = *yp + v + bias_r[nj];
        } else if (EPI == 2) {
          bout[(long)m * 1024 + n] = f2b(gelu_fast(v + bias_r[nj]));
        }
      }
}

// ---------- per-window attention ----------
__global__ __launch_bounds__(256)
void attn_win(const u16* __restrict__ qkv, const float* __restrict__ rpb,
              u16* __restrict__ aout) {
  __shared__ float Pls[4][64 * 66];
  __shared__ float srpb[1800];
  const int tid = threadIdx.x, lane = tid & 63, wv = tid >> 6;
  const int r = blockIdx.x;
  for (int i = tid; i < 1800; i += 256) srpb[i] = rpb[i];
  __syncthreads();

  // reference quirk: jnp.repeat(mask, B, axis=0) -> window r uses mask[r/4]
  const int midx = r >> 2;
  const int wh = midx / 28, ww = midx % 28;
  const int l15 = lane & 15, l4 = lane >> 4;

  float* Pw = &Pls[wv][0];
  const u16* kb = qkv + 51380224;
  const u16* vb = qkv + 102760448;

  int rj[4], cj[4], labj[4];
#pragma unroll
  for (int nj = 0; nj < 4; ++nj) {
    const int j = nj * 16 + l15;
    rj[nj] = j >> 3; cj[nj] = j & 7;
    const int hp = wh * 8 + rj[nj], wp = ww * 8 + cj[nj];
    const int lh = (hp < 216) ? 0 : ((hp < 220) ? 1 : 2);
    const int lw = (wp < 216) ? 0 : ((wp < 220) ? 1 : 2);
    labj[nj] = lh * 3 + lw;
  }

  const f32x4 vzero = {0.f, 0.f, 0.f, 0.f};
  for (int hh = 0; hh < 2; ++hh) {
    const int h = wv * 2 + hh;
    const long hb = (long)(r * 8 + h) * 2048;
    const u16* qh = qkv + hb;
    const u16* kh = kb + hb;
    const u16* vh = vb + hb;

    bf16x8 qf[4], kf[4];
#pragma unroll
    for (int mi = 0; mi < 4; ++mi)
      qf[mi] = *(const bf16x8*)(qh + (mi * 16 + l15) * 32 + l4 * 8);
#pragma unroll
    for (int nj = 0; nj < 4; ++nj)
      kf[nj] = *(const bf16x8*)(kh + (nj * 16 + l15) * 32 + l4 * 8);

    f32x4 S[4][4];
#pragma unroll
    for (int mi = 0; mi < 4; ++mi)
#pragma unroll
      for (int nj = 0; nj < 4; ++nj)
        S[mi][nj] = __builtin_amdgcn_mfma_f32_16x16x32_bf16(qf[mi], kf[nj], vzero, 0, 0, 0);

    float rsave[4][4];
#pragma unroll
    for (int mi = 0; mi < 4; ++mi)
#pragma unroll
      for (int reg = 0; reg < 4; ++reg) {
        const int i = mi * 16 + (l4 << 2) + reg;
        const int ri = i >> 3, ci = i & 7;
        const int hp = wh * 8 + ri, wp = ww * 8 + ci;
        const int lh = (hp < 216) ? 0 : ((hp < 220) ? 1 : 2);
        const int lw = (wp < 216) ? 0 : ((wp < 220) ? 1 : 2);
        const int li = lh * 3 + lw;
        float v[4];
#pragma unroll
        for (int nj = 0; nj < 4; ++nj) {
          const int idx = (ri - rj[nj] + 7) * 15 + (ci - cj[nj] + 7);
          v[nj] = S[mi][nj][reg] * 0.17677669529663687f + srpb[idx * 8 + h]
                + ((li != labj[nj]) ? -100.0f : 0.0f);
        }
        float mx = fmaxf(fmaxf(v[0], v[1]), fmaxf(v[2], v[3]));
        mx = fmaxf(mx, __shfl_xor(mx, 1));
        mx = fmaxf(mx, __shfl_xor(mx, 2));
        mx = fmaxf(mx, __shfl_xor(mx, 4));
        mx = fmaxf(mx, __shfl_xor(mx, 8));
        float sum = 0.f;
#pragma unroll
        for (int nj = 0; nj < 4; ++nj) { v[nj] = __expf(v[nj] - mx); sum += v[nj]; }
        sum += __shfl_xor(sum, 1);
        sum += __shfl_xor(sum, 2);
        sum += __shfl_xor(sum, 4);
        sum += __shfl_xor(sum, 8);
        rsave[mi][reg] = 1.0f / sum;          // deferred normalization
#pragma unroll
        for (int nj = 0; nj < 4; ++nj) Pw[i * 66 + nj * 16 + l15] = v[nj];
      }

    f32x4 O[4][2];
#pragma unroll
    for (int mi = 0; mi < 4; ++mi) { O[mi][0] = vzero; O[mi][1] = vzero; }
#pragma unroll
    for (int kk = 0; kk < 2; ++kk) {
      bf16x8 pf[4], vf[2];
#pragma unroll
      for (int mi = 0; mi < 4; ++mi) {
        const int base = (mi * 16 + l15) * 66 + kk * 32 + l4 * 8;
        bf16x8 t;
#pragma unroll
        for (int e = 0; e < 8; ++e) t[e] = (__bf16)Pw[base + e];
        pf[mi] = t;
      }
#pragma unroll
      for (int nd = 0; nd < 2; ++nd)
        vf[nd] = *(const bf16x8*)(vh + (nd * 16 + l15) * 64 + kk * 32 + l4 * 8);
#pragma unroll
      for (int mi = 0; mi < 4; ++mi)
#pragma unroll
        for (int nd = 0; nd < 2; ++nd)
          O[mi][nd] = __builtin_amdgcn_mfma_f32_16x16x32_bf16(pf[mi], vf[nd], O[mi][nd], 0, 0, 0);
    }

#pragma unroll
    for (int mi = 0; mi < 4; ++mi)
#pragma unroll
      for (int nd = 0; nd < 2; ++nd)
#pragma unroll
        for (int reg = 0; reg < 4; ++reg) {
          const int i = mi * 16 + (l4 << 2) + reg;
          aout[(long)(r * 64 + i) * 256 + h * 32 + nd * 16 + l15] =
              f2b(O[mi][nd][reg] * rsave[mi][reg]);
        }
  }
}

// ---------- rowwise LN2 ----------
__global__ __launch_bounds__(256)
void ln2_rows(const float* __restrict__ y, const float* __restrict__ w,
              const float* __restrict__ bb, u16* __restrict__ out) {
  const int lane = threadIdx.x & 63;
  const long row = (long)blockIdx.x * 4 + (threadIdx.x >> 6);
  const float4 v = *(const float4*)(y + row * 256 + lane * 4);
  float s = v.x + v.y + v.z + v.w;
  float q = v.x * v.x + v.y * v.y + v.z * v.z + v.w * v.w;
#pragma unroll
  for (int d = 1; d < 64; d <<= 1) { s += __shfl_xor(s, d); q += __shfl_xor(q, d); }
  const float mean = s * (1.f / 256.f);
  const float rstd = rsqrtf(q * (1.f / 256.f) - mean * mean + 1e-5f);
  const int c = lane * 4;
  u16x4 o;
  o[0] = f2b((v.x - mean) * rstd * w[c + 0] + bb[c + 0]);
  o[1] = f2b((v.y - mean) * rstd * w[c + 1] + bb[c + 1]);
  o[2] = f2b((v.z - mean) * rstd * w[c + 2] + bb[c + 2]);
  o[3] = f2b((v.w - mean) * rstd * w[c + 3] + bb[c + 3]);
  *(u16x4*)(out + row * 256 + c) = o;
}

// ---------- un-window scatter, 4 adjacent windows per block ----------
__global__ __launch_bounds__(256)
void unwin(const float* __restrict__ y, float* __restrict__ out) {
  __shared__ float xt[64 * 257];
  const int tid = threadIdx.x, lane = tid & 63, wv = tid >> 6;
  const int g = blockIdx.x;
  const int b = g / 196, rem = g % 196;
  const int wh = rem / 7, wg = rem % 7;
  const int base_r = b * 784 + wh * 28 + wg * 4;
  const int pr = tid >> 5, pc = tid & 31;
  int hp = wh * 8 + 4 + pr; if (hp >= 224) hp -= 224;
  int wp = wg * 32 + 4 + pc; if (wp >= 224) wp -= 224;
  const long woff = (long)b * 256 * 50176 + hp * 224 + wp;

  for (int cc = 0; cc < 4; ++cc) {
#pragma unroll 8
    for (int jj = 0; jj < 64; ++jj) {
      const int p = jj * 4 + wv;
      const int m = (base_r + ((p & 31) >> 3)) * 64 + (p >> 5) * 8 + (p & 7);
      xt[lane * 257 + p] = y[(long)m * 256 + cc * 64 + lane];
    }
    __syncthreads();
#pragma unroll 8
    for (int i = 0; i < 64; ++i)
      out[(long)(cc * 64 + i) * 50176 + woff] = xt[i * 257 + tid];
    __syncthreads();
  }
}

// ---------- launch ----------
extern "C" void kernel_launch(void* const* d_in, const int* in_sizes, int n_in,
                              void* d_out, int out_size, void* d_ws, size_t ws_size,
                              hipStream_t stream) {
  (void)in_sizes; (void)n_in; (void)out_size; (void)ws_size;
  const float* x     = (const float*)d_in[0];
  const float* qkvw  = (const float*)d_in[1];
  const float* projw = (const float*)d_in[2];
  const float* projb = (const float*)d_in[3];
  const float* rpb   = (const float*)d_in[4];
  const float* n1w   = (const float*)d_in[5];
  const float* n1b   = (const float*)d_in[6];
  const float* n2w   = (const float*)d_in[7];
  const float* n2b   = (const float*)d_in[8];
  const float* w1    = (const float*)d_in[9];
  const float* b1    = (const float*)d_in[10];
  const float* w2    = (const float*)d_in[11];
  const float* b2    = (const float*)d_in[12];

  char* ws = (char*)d_ws;
  u16*   hbuf   = (u16*)(ws);                  // 102,760,448 B : h, later h2
  u16*   qkvb   = (u16*)(ws + 102760448);      // 308,281,344 B : q|k|v
  u16*   abuf   = (u16*)(ws + 411041792);      // 102,760,448 B : attn out
  float* ybuf   = (float*)(ws + 513802240);    // 205,520,896 B : fp32 residual stream
  u16*   hidb   = (u16*)(ws + 102760448);      // 411,041,792 B : overlays qkv+attn (dead by then)
  u16*   qkvwb  = (u16*)(ws + 719323136);
  u16*   projwb = (u16*)(ws + 719716352);
  u16*   w1b    = (u16*)(ws + 719847424);
  u16*   w2b    = (u16*)(ws + 720371712);      // end: 720,896,000 B

  conv_weights<<<3072, 256, 0, stream>>>(qkvw, projw, w1, w2, qkvwb, projwb, w1b, w2b);
  ln1_win<<<784, 256, 0, stream>>>(x, n1w, n1b, hbuf, ybuf);
  gemm_bt<0, 6><<<9408, 256, 0, stream>>>(hbuf, qkvwb, 256, nullptr, nullptr, qkvb);
  attn_win<<<3136, 256, 0, stream>>>(qkvb, rpb, abuf);
  gemm_bt<1, 2><<<3136, 256, 0, stream>>>(abuf, projwb, 256, ybuf, projb, nullptr);
  ln2_rows<<<50176, 256, 0, stream>>>(ybuf, n2w, n2b, hbuf);
  gemm_bt<2, 8><<<12544, 256, 0, stream>>>(hbuf, w1b, 256, nullptr, b1, hidb);
  gemm_bt<3, 2><<<3136, 256, 0, stream>>>(hidb, w2b, 1024, ybuf, b2, nullptr);
  unwin<<<784, 256, 0, stream>>>(ybuf, (float*)d_out);
}

// Round 5
// 1414.158 us; speedup vs baseline: 1.2377x; 1.0205x over previous
//
#include <hip/hip_runtime.h>

typedef unsigned short u16;
typedef unsigned int   u32;
typedef __attribute__((ext_vector_type(8))) __bf16 bf16x8;
typedef __attribute__((ext_vector_type(4))) float  f32x4;
typedef __attribute__((ext_vector_type(4))) u16    u16x4;
typedef __attribute__((ext_vector_type(8))) u16    u16x8;

#define DEV __device__ __forceinline__

// ---------- helpers ----------
DEV u16 f2b(float f) {               // fp32 -> bf16 bits, RNE
  union { float f; u32 u; } a; a.f = f;
  const u32 u = a.u;
  return (u16)((u + 0x7fffu + ((u >> 16) & 1u)) >> 16);
}

// tanh-form GELU as x*sigmoid(1.5957691*(x+0.044715 x^3)); exp2-folded.
DEV float gelu_fast(float x) {
  const float x2 = x * x;
  const float t  = __builtin_fmaf(0.1029430f, x2, 2.3022150f);  // *log2(e) folded
  const float e  = __builtin_exp2f(x * t);
  const float r  = __builtin_amdgcn_rcpf(1.0f + e);
  return __builtin_fmaf(-x, r, x);   // x - x/(1+e) = x*sigmoid(z)
}

DEV void gload16(const void* g, void* l) {
  __builtin_amdgcn_global_load_lds(
      (const __attribute__((address_space(1))) void*)g,
      (__attribute__((address_space(3))) void*)l, 16, 0, 0);
}

// ---------- weight conversion (fp32 -> bf16) ----------
__global__ __launch_bounds__(256)
void conv_weights(const float* __restrict__ qkvw, const float* __restrict__ projw,
                  const float* __restrict__ w1,   const float* __restrict__ w2,
                  u16* __restrict__ dq, u16* __restrict__ dp,
                  u16* __restrict__ d1, u16* __restrict__ d2) {
  const int t = blockIdx.x * 256 + threadIdx.x;
  if (t < 196608)      dq[t]          = f2b(qkvw[t]);
  else if (t < 262144) dp[t - 196608] = f2b(projw[t - 196608]);
  else if (t < 524288) d1[t - 262144] = f2b(w1[t - 262144]);
  else                 d2[t - 524288] = f2b(w2[t - 524288]);
}

// ---------- window gather + LN1, 4 adjacent windows per block ----------
__global__ __launch_bounds__(256)
void ln1_win(const float* __restrict__ x, const float* __restrict__ w1,
             const float* __restrict__ b1, u16* __restrict__ hout,
             float* __restrict__ xwout) {
  __shared__ float xt[64 * 257];
  __shared__ float smean[256], srstd[256];
  const int tid = threadIdx.x, lane = tid & 63, wv = tid >> 6;
  const int g = blockIdx.x;
  const int b = g / 196, rem = g % 196;
  const int wh = rem / 7, wg = rem % 7;
  const int base_r = b * 784 + wh * 28 + wg * 4;
  const int pr = tid >> 5, pc = tid & 31;
  int hp = wh * 8 + 4 + pr; if (hp >= 224) hp -= 224;
  int wp = wg * 32 + 4 + pc; if (wp >= 224) wp -= 224;
  const long roff = (long)b * 256 * 50176 + hp * 224 + wp;

  float s = 0.f, q = 0.f;
  for (int cc = 0; cc < 4; ++cc) {
#pragma unroll 8
    for (int i = 0; i < 64; ++i) {
      const int c = cc * 64 + i;
      const float v = x[(long)c * 50176 + roff];
      xt[i * 257 + tid] = v;
      s += v; q += v * v;
    }
    __syncthreads();
#pragma unroll 8
    for (int jj = 0; jj < 64; ++jj) {
      const int p = jj * 4 + wv;
      const int m = (base_r + ((p & 31) >> 3)) * 64 + (p >> 5) * 8 + (p & 7);
      xwout[(long)m * 256 + cc * 64 + lane] = xt[lane * 257 + p];
    }
    __syncthreads();
  }
  const float mean = s * (1.f / 256.f);
  smean[tid] = mean;
  srstd[tid] = rsqrtf(q * (1.f / 256.f) - mean * mean + 1e-5f);
  __syncthreads();

  float wr_[4], br_[4];
#pragma unroll
  for (int cc = 0; cc < 4; ++cc) { wr_[cc] = w1[cc * 64 + lane]; br_[cc] = b1[cc * 64 + lane]; }
#pragma unroll 2
  for (int jj = 0; jj < 64; ++jj) {
    const int p = jj * 4 + wv;
    const int m = (base_r + ((p & 31) >> 3)) * 64 + (p >> 5) * 8 + (p & 7);
    const float mu = smean[p], rs = srstd[p];
#pragma unroll
    for (int cc = 0; cc < 4; ++cc) {
      const float v = xwout[(long)m * 256 + cc * 64 + lane];
      hout[(long)m * 256 + cc * 64 + lane] = f2b((v - mu) * rs * wr_[cc] + br_[cc]);
    }
  }
}

// ---------- 256x256x(BK=64) bf16 GEMM, B given as [N][K], 8 waves (2x4) ----------
// 2-phase double-buffered global_load_lds staging, T2 k-slot XOR swizzle,
// 1-D grid with XCD chunk swizzle + column-fast decode.
// Operand-swapped MFMA (n in reg-dim) for all EPIs except v (EPI 5).
// EPI 0: q|k scatter, u16x4 along d          (NCOL=2, cols 0..511)
// EPI 5: v^T scatter, u16x4 along ii         (NCOL=1, col0=512)
// EPI 1/3: y[m][n] += acc + bias, float4 RMW (NCOL=1)
// EPI 2: hidden = bf16(gelu(acc+b)), u16x4   (NCOL=4, ldc=1024)
template<int EPI, int NCOL>
__global__ __launch_bounds__(512, 2)
void gemm_bt(const u16* __restrict__ A, const u16* __restrict__ Bw, const int K,
             float* __restrict__ fout, const float* __restrict__ bias,
             u16* __restrict__ bout) {
  __shared__ __align__(16) u16 smem[65536];   // 128 KB
  u16* sA0 = smem;
  u16* sB0 = smem + 16384;
  u16* sA1 = smem + 32768;
  u16* sB1 = smem + 49152;

  const int tid  = threadIdx.x;
  const int lane = tid & 63;
  const int wid  = tid >> 6;       // 0..7
  const int wr   = wid >> 2;       // 0..1  (row half)
  const int wc   = wid & 3;        // 0..3  (col quarter)

  const int nwg = gridDim.x;
  const int bid = blockIdx.x;
  const int wg  = (bid & 7) * (nwg >> 3) + (bid >> 3);   // XCD chunk swizzle
  const int row_blk = wg / NCOL;                          // column-fast
  const int col_blk = wg - row_blk * NCOL;
  const int row0 = row_blk * 256;
  const int col0 = (EPI == 5) ? 512 : col_blk * 256;

  const f32x4 vzero = {0.f, 0.f, 0.f, 0.f};
  f32x4 acc[8][4];
#pragma unroll
  for (int i = 0; i < 8; ++i)
#pragma unroll
    for (int j = 0; j < 4; ++j) acc[i][j] = vzero;

  const int lrow = lane >> 3;
  const int lcol = ((lane & 7) << 3) ^ (lane & 56);  // pre-swizzled source k-offset
  const int l15  = lane & 15;
  const int l4   = lane >> 4;
  const int ksw  = (lane & 7) << 3;                  // ds_read swizzle

  const u16* pA = A  + (long)(row0 + lrow) * K + lcol;
  const u16* pB = Bw + (long)(col0 + lrow) * K + lcol;

#define STAGE_TILE(KT, DA, DB)                                       \
  {                                                                  \
    _Pragma("unroll")                                                \
    for (int ch = 0; ch < 4; ++ch) {                                 \
      const int rr = ch * 64 + wid * 8;                              \
      gload16(pA + (long)rr * K + (KT), (DA) + rr * 64);             \
      gload16(pB + (long)rr * K + (KT), (DB) + rr * 64);             \
    }                                                                \
  }

#define COMPUTE_TILE(SA, SB)                                                            \
  {                                                                                     \
    _Pragma("unroll")                                                                   \
    for (int kk = 0; kk < 2; ++kk) {                                                    \
      bf16x8 af[8], bfv[4];                                                             \
      _Pragma("unroll")                                                                 \
      for (int mi = 0; mi < 8; ++mi)                                                    \
        af[mi] = *(const bf16x8*)((SA) + (wr * 128 + mi * 16 + l15) * 64 +              \
                                  ((kk * 32 + l4 * 8) ^ ksw));                          \
      _Pragma("unroll")                                                                 \
      for (int nj = 0; nj < 4; ++nj)                                                    \
        bfv[nj] = *(const bf16x8*)((SB) + (wc * 64 + nj * 16 + l15) * 64 +              \
                                   ((kk * 32 + l4 * 8) ^ ksw));                         \
      _Pragma("unroll")                                                                 \
      for (int mi = 0; mi < 8; ++mi)                                                    \
        _Pragma("unroll")                                                               \
        for (int nj = 0; nj < 4; ++nj) {                                                \
          if (EPI == 5)                                                                 \
            acc[mi][nj] = __builtin_amdgcn_mfma_f32_16x16x32_bf16(af[mi], bfv[nj],      \
                                                                  acc[mi][nj], 0, 0, 0);\
          else                                                                          \
            acc[mi][nj] = __builtin_amdgcn_mfma_f32_16x16x32_bf16(bfv[nj], af[mi],      \
                                                                  acc[mi][nj], 0, 0, 0);\
        }                                                                               \
    }                                                                                   \
  }

  const int nt = K >> 6;
  STAGE_TILE(0, sA0, sB0);
  __syncthreads();
  for (int t = 0; t < nt; t += 2) {
    if (t + 1 < nt) STAGE_TILE((t + 1) << 6, sA1, sB1);
    COMPUTE_TILE(sA0, sB0);
    __syncthreads();
    if (t + 1 < nt) {
      if (t + 2 < nt) STAGE_TILE((t + 2) << 6, sA0, sB0);
      COMPUTE_TILE(sA1, sB1);
      __syncthreads();
    }
  }
#undef STAGE_TILE
#undef COMPUTE_TILE

  if (EPI == 0) {
    // q|k scatter, swapped orientation: lane=m, reg=n(d)
#pragma unroll
    for (int mi = 0; mi < 8; ++mi) {
      const int m = row0 + wr * 128 + mi * 16 + l15;
      const int rr = m >> 6, ii = m & 63;
#pragma unroll
      for (int nj = 0; nj < 4; ++nj) {
        const int n = col0 + wc * 64 + nj * 16 + (l4 << 2);
        const int s = n >> 8, hh = (n >> 5) & 7, d = n & 31;
        u16x4 p;
#pragma unroll
        for (int reg = 0; reg < 4; ++reg) p[reg] = f2b(acc[mi][nj][reg]);
        *(u16x4*)(bout + (long)s * 51380224L +
                  (long)((rr * 8 + hh) * 64 + ii) * 32 + d) = p;
      }
    }
  } else if (EPI == 5) {
    // v^T scatter, original orientation: lane=n(d), reg=m(ii)
#pragma unroll
    for (int mi = 0; mi < 8; ++mi) {
      const int mb = row0 + wr * 128 + mi * 16 + (l4 << 2);
      const int rrg = mb >> 6, ii = mb & 63;
#pragma unroll
      for (int nj = 0; nj < 4; ++nj) {
        const int n = 512 + wc * 64 + nj * 16 + l15;
        const int hh = (n >> 5) & 7, d = n & 31;
        u16x4 p;
#pragma unroll
        for (int reg = 0; reg < 4; ++reg) p[reg] = f2b(acc[mi][nj][reg]);
        *(u16x4*)(bout + 102760448L + (long)((rrg * 8 + hh) * 32 + d) * 64 + ii) = p;
      }
    }
  } else if (EPI == 1 || EPI == 3) {
    // y += acc + bias, float4 RMW (N=256, col0=0)
    f32x4 b4[4];
#pragma unroll
    for (int nj = 0; nj < 4; ++nj)
      b4[nj] = *(const f32x4*)(bias + wc * 64 + nj * 16 + (l4 << 2));
#pragma unroll
    for (int mi = 0; mi < 8; ++mi) {
      const int m = row0 + wr * 128 + mi * 16 + l15;
      float* yrow = fout + (long)m * 256;
#pragma unroll
      for (int nj = 0; nj < 4; ++nj) {
        const int n = wc * 64 + nj * 16 + (l4 << 2);
        f32x4 o = *(f32x4*)(yrow + n);
#pragma unroll
        for (int reg = 0; reg < 4; ++reg) o[reg] += acc[mi][nj][reg] + b4[nj][reg];
        *(f32x4*)(yrow + n) = o;
      }
    }
  } else {
    // EPI 2: hidden = bf16(gelu(acc+bias)), u16x4 along n, ldc=1024
    f32x4 b4[4];
#pragma unroll
    for (int nj = 0; nj < 4; ++nj)
      b4[nj] = *(const f32x4*)(bias + col0 + wc * 64 + nj * 16 + (l4 << 2));
#pragma unroll
    for (int mi = 0; mi < 8; ++mi) {
      const int m = row0 + wr * 128 + mi * 16 + l15;
#pragma unroll
      for (int nj = 0; nj < 4; ++nj) {
        const int n = col0 + wc * 64 + nj * 16 + (l4 << 2);
        u16x4 p;
#pragma unroll
        for (int reg = 0; reg < 4; ++reg)
          p[reg] = f2b(gelu_fast(acc[mi][nj][reg] + b4[nj][reg]));
        *(u16x4*)(bout + (long)m * 1024 + n) = p;
      }
    }
  }
}

// ---------- per-window attention ----------
__global__ __launch_bounds__(256)
void attn_win(const u16* __restrict__ qkv, const float* __restrict__ rpb,
              u16* __restrict__ aout) {
  __shared__ float Pls[4][64 * 66];
  __shared__ float srpb[1800];
  const int tid = threadIdx.x, lane = tid & 63, wv = tid >> 6;
  const int r = blockIdx.x;
  for (int i = tid; i < 1800; i += 256) srpb[i] = rpb[i];
  __syncthreads();

  // reference quirk: jnp.repeat(mask, B, axis=0) -> window r uses mask[r/4]
  const int midx = r >> 2;
  const int wh = midx / 28, ww = midx % 28;
  const int l15 = lane & 15, l4 = lane >> 4;

  float* Pw = &Pls[wv][0];
  const u16* kb = qkv + 51380224;
  const u16* vb = qkv + 102760448;

  int rj[4], cj[4], labj[4];
#pragma unroll
  for (int nj = 0; nj < 4; ++nj) {
    const int j = nj * 16 + l15;
    rj[nj] = j >> 3; cj[nj] = j & 7;
    const int hp = wh * 8 + rj[nj], wp = ww * 8 + cj[nj];
    const int lh = (hp < 216) ? 0 : ((hp < 220) ? 1 : 2);
    const int lw = (wp < 216) ? 0 : ((wp < 220) ? 1 : 2);
    labj[nj] = lh * 3 + lw;
  }

  const f32x4 vzero = {0.f, 0.f, 0.f, 0.f};
  for (int hh = 0; hh < 2; ++hh) {
    const int h = wv * 2 + hh;
    const long hb = (long)(r * 8 + h) * 2048;
    const u16* qh = qkv + hb;
    const u16* kh = kb + hb;
    const u16* vh = vb + hb;

    bf16x8 qf[4], kf[4];
#pragma unroll
    for (int mi = 0; mi < 4; ++mi)
      qf[mi] = *(const bf16x8*)(qh + (mi * 16 + l15) * 32 + l4 * 8);
#pragma unroll
    for (int nj = 0; nj < 4; ++nj)
      kf[nj] = *(const bf16x8*)(kh + (nj * 16 + l15) * 32 + l4 * 8);

    f32x4 S[4][4];
#pragma unroll
    for (int mi = 0; mi < 4; ++mi)
#pragma unroll
      for (int nj = 0; nj < 4; ++nj)
        S[mi][nj] = __builtin_amdgcn_mfma_f32_16x16x32_bf16(qf[mi], kf[nj], vzero, 0, 0, 0);

    float rsave[4][4];
#pragma unroll
    for (int mi = 0; mi < 4; ++mi)
#pragma unroll
      for (int reg = 0; reg < 4; ++reg) {
        const int i = mi * 16 + (l4 << 2) + reg;
        const int ri = i >> 3, ci = i & 7;
        const int hp = wh * 8 + ri, wp = ww * 8 + ci;
        const int lh = (hp < 216) ? 0 : ((hp < 220) ? 1 : 2);
        const int lw = (wp < 216) ? 0 : ((wp < 220) ? 1 : 2);
        const int li = lh * 3 + lw;
        float v[4];
#pragma unroll
        for (int nj = 0; nj < 4; ++nj) {
          const int idx = (ri - rj[nj] + 7) * 15 + (ci - cj[nj] + 7);
          v[nj] = S[mi][nj][reg] * 0.17677669529663687f + srpb[idx * 8 + h]
                + ((li != labj[nj]) ? -100.0f : 0.0f);
        }
        float mx = fmaxf(fmaxf(v[0], v[1]), fmaxf(v[2], v[3]));
        mx = fmaxf(mx, __shfl_xor(mx, 1));
        mx = fmaxf(mx, __shfl_xor(mx, 2));
        mx = fmaxf(mx, __shfl_xor(mx, 4));
        mx = fmaxf(mx, __shfl_xor(mx, 8));
        float sum = 0.f;
#pragma unroll
        for (int nj = 0; nj < 4; ++nj) { v[nj] = __expf(v[nj] - mx); sum += v[nj]; }
        sum += __shfl_xor(sum, 1);
        sum += __shfl_xor(sum, 2);
        sum += __shfl_xor(sum, 4);
        sum += __shfl_xor(sum, 8);
        rsave[mi][reg] = 1.0f / sum;          // deferred normalization
#pragma unroll
        for (int nj = 0; nj < 4; ++nj) Pw[i * 66 + nj * 16 + l15] = v[nj];
      }

    f32x4 O[4][2];
#pragma unroll
    for (int mi = 0; mi < 4; ++mi) { O[mi][0] = vzero; O[mi][1] = vzero; }
#pragma unroll
    for (int kk = 0; kk < 2; ++kk) {
      bf16x8 pf[4], vf[2];
#pragma unroll
      for (int mi = 0; mi < 4; ++mi) {
        const int base = (mi * 16 + l15) * 66 + kk * 32 + l4 * 8;
        bf16x8 t;
#pragma unroll
        for (int e = 0; e < 8; ++e) t[e] = (__bf16)Pw[base + e];
        pf[mi] = t;
      }
#pragma unroll
      for (int nd = 0; nd < 2; ++nd)
        vf[nd] = *(const bf16x8*)(vh + (nd * 16 + l15) * 64 + kk * 32 + l4 * 8);
#pragma unroll
      for (int mi = 0; mi < 4; ++mi)
#pragma unroll
        for (int nd = 0; nd < 2; ++nd)
          O[mi][nd] = __builtin_amdgcn_mfma_f32_16x16x32_bf16(pf[mi], vf[nd], O[mi][nd], 0, 0, 0);
    }

#pragma unroll
    for (int mi = 0; mi < 4; ++mi)
#pragma unroll
      for (int nd = 0; nd < 2; ++nd)
#pragma unroll
        for (int reg = 0; reg < 4; ++reg) {
          const int i = mi * 16 + (l4 << 2) + reg;
          aout[(long)(r * 64 + i) * 256 + h * 32 + nd * 16 + l15] =
              f2b(O[mi][nd][reg] * rsave[mi][reg]);
        }
  }
}

// ---------- rowwise LN2 ----------
__global__ __launch_bounds__(256)
void ln2_rows(const float* __restrict__ y, const float* __restrict__ w,
              const float* __restrict__ bb, u16* __restrict__ out) {
  const int lane = threadIdx.x & 63;
  const long row = (long)blockIdx.x * 4 + (threadIdx.x >> 6);
  const float4 v = *(const float4*)(y + row * 256 + lane * 4);
  float s = v.x + v.y + v.z + v.w;
  float q = v.x * v.x + v.y * v.y + v.z * v.z + v.w * v.w;
#pragma unroll
  for (int d = 1; d < 64; d <<= 1) { s += __shfl_xor(s, d); q += __shfl_xor(q, d); }
  const float mean = s * (1.f / 256.f);
  const float rstd = rsqrtf(q * (1.f / 256.f) - mean * mean + 1e-5f);
  const int c = lane * 4;
  u16x4 o;
  o[0] = f2b((v.x - mean) * rstd * w[c + 0] + bb[c + 0]);
  o[1] = f2b((v.y - mean) * rstd * w[c + 1] + bb[c + 1]);
  o[2] = f2b((v.z - mean) * rstd * w[c + 2] + bb[c + 2]);
  o[3] = f2b((v.w - mean) * rstd * w[c + 3] + bb[c + 3]);
  *(u16x4*)(out + row * 256 + c) = o;
}

// ---------- un-window scatter, 4 adjacent windows per block ----------
__global__ __launch_bounds__(256)
void unwin(const float* __restrict__ y, float* __restrict__ out) {
  __shared__ float xt[64 * 257];
  const int tid = threadIdx.x, lane = tid & 63, wv = tid >> 6;
  const int g = blockIdx.x;
  const int b = g / 196, rem = g % 196;
  const int wh = rem / 7, wg = rem % 7;
  const int base_r = b * 784 + wh * 28 + wg * 4;
  const int pr = tid >> 5, pc = tid & 31;
  int hp = wh * 8 + 4 + pr; if (hp >= 224) hp -= 224;
  int wp = wg * 32 + 4 + pc; if (wp >= 224) wp -= 224;
  const long woff = (long)b * 256 * 50176 + hp * 224 + wp;

  for (int cc = 0; cc < 4; ++cc) {
#pragma unroll 8
    for (int jj = 0; jj < 64; ++jj) {
      const int p = jj * 4 + wv;
      const int m = (base_r + ((p & 31) >> 3)) * 64 + (p >> 5) * 8 + (p & 7);
      xt[lane * 257 + p] = y[(long)m * 256 + cc * 64 + lane];
    }
    __syncthreads();
#pragma unroll 8
    for (int i = 0; i < 64; ++i)
      out[(long)(cc * 64 + i) * 50176 + woff] = xt[i * 257 + tid];
    __syncthreads();
  }
}

// ---------- launch ----------
extern "C" void kernel_launch(void* const* d_in, const int* in_sizes, int n_in,
                              void* d_out, int out_size, void* d_ws, size_t ws_size,
                              hipStream_t stream) {
  (void)in_sizes; (void)n_in; (void)out_size; (void)ws_size;
  const float* x     = (const float*)d_in[0];
  const float* qkvw  = (const float*)d_in[1];
  const float* projw = (const float*)d_in[2];
  const float* projb = (const float*)d_in[3];
  const float* rpb   = (const float*)d_in[4];
  const float* n1w   = (const float*)d_in[5];
  const float* n1b   = (const float*)d_in[6];
  const float* n2w   = (const float*)d_in[7];
  const float* n2b   = (const float*)d_in[8];
  const float* w1    = (const float*)d_in[9];
  const float* b1    = (const float*)d_in[10];
  const float* w2    = (const float*)d_in[11];
  const float* b2    = (const float*)d_in[12];

  char* ws = (char*)d_ws;
  u16*   hbuf   = (u16*)(ws);                  // 102,760,448 B : h, later h2
  u16*   qkvb   = (u16*)(ws + 102760448);      // 308,281,344 B : q|k|v
  u16*   abuf   = (u16*)(ws + 411041792);      // 102,760,448 B : attn out
  float* ybuf   = (float*)(ws + 513802240);    // 205,520,896 B : fp32 residual stream
  u16*   hidb   = (u16*)(ws + 102760448);      // 411,041,792 B : overlays qkv+attn (dead by then)
  u16*   qkvwb  = (u16*)(ws + 719323136);
  u16*   projwb = (u16*)(ws + 719716352);
  u16*   w1b    = (u16*)(ws + 719847424);
  u16*   w2b    = (u16*)(ws + 720371712);      // end: 720,896,000 B

  conv_weights<<<3072, 256, 0, stream>>>(qkvw, projw, w1, w2, qkvwb, projwb, w1b, w2b);
  ln1_win<<<784, 256, 0, stream>>>(x, n1w, n1b, hbuf, ybuf);
  gemm_bt<0, 2><<<1568, 512, 0, stream>>>(hbuf, qkvwb, 256, nullptr, nullptr, qkvb);
  gemm_bt<5, 1><<<784, 512, 0, stream>>>(hbuf, qkvwb, 256, nullptr, nullptr, qkvb);
  attn_win<<<3136, 256, 0, stream>>>(qkvb, rpb, abuf);
  gemm_bt<1, 1><<<784, 512, 0, stream>>>(abuf, projwb, 256, ybuf, projb, nullptr);
  ln2_rows<<<50176, 256, 0, stream>>>(ybuf, n2w, n2b, hbuf);
  gemm_bt<2, 4><<<3136, 512, 0, stream>>>(hbuf, w1b, 256, nullptr, b1, hidb);
  gemm_bt<3, 1><<<784, 512, 0, stream>>>(hidb, w2b, 1024, ybuf, b2, nullptr);
  unwin<<<784, 256, 0, stream>>>(ybuf, (float*)d_out);
}

// Round 6
// 1256.682 us; speedup vs baseline: 1.3928x; 1.1253x over previous
//
#include <hip/hip_runtime.h>

typedef unsigned short u16;
typedef unsigned int   u32;
typedef __attribute__((ext_vector_type(8))) __bf16 bf16x8;
typedef __attribute__((ext_vector_type(4))) float  f32x4;
typedef __attribute__((ext_vector_type(4))) u16    u16x4;
typedef __attribute__((ext_vector_type(8))) u16    u16x8;

#define DEV __device__ __forceinline__

// ---------- helpers ----------
DEV u16 f2b(float f) {               // fp32 -> bf16 bits, RNE
  union { float f; u32 u; } a; a.f = f;
  const u32 u = a.u;
  return (u16)((u + 0x7fffu + ((u >> 16) & 1u)) >> 16);
}

// tanh-form GELU as x*sigmoid(1.5957691*(x+0.044715 x^3)); exp2-folded.
DEV float gelu_fast(float x) {
  const float x2 = x * x;
  const float t  = __builtin_fmaf(0.1029430f, x2, 2.3022150f);  // *log2(e) folded
  const float e  = __builtin_exp2f(x * t);
  const float r  = __builtin_amdgcn_rcpf(1.0f + e);
  return __builtin_fmaf(-x, r, x);   // x - x/(1+e) = x*sigmoid(z)
}

DEV void gload16(const void* g, void* l) {
  __builtin_amdgcn_global_load_lds(
      (const __attribute__((address_space(1))) void*)g,
      (__attribute__((address_space(3))) void*)l, 16, 0, 0);
}

// ---------- weight conversion (fp32 -> bf16) ----------
__global__ __launch_bounds__(256)
void conv_weights(const float* __restrict__ qkvw, const float* __restrict__ projw,
                  const float* __restrict__ w1,   const float* __restrict__ w2,
                  u16* __restrict__ dq, u16* __restrict__ dp,
                  u16* __restrict__ d1, u16* __restrict__ d2) {
  const int t = blockIdx.x * 256 + threadIdx.x;
  if (t < 196608)      dq[t]          = f2b(qkvw[t]);
  else if (t < 262144) dp[t - 196608] = f2b(projw[t - 196608]);
  else if (t < 524288) d1[t - 262144] = f2b(w1[t - 262144]);
  else                 d2[t - 524288] = f2b(w2[t - 524288]);
}

// ---------- window gather + LN1, 4 adjacent windows per block ----------
__global__ __launch_bounds__(256)
void ln1_win(const float* __restrict__ x, const float* __restrict__ w1,
             const float* __restrict__ b1, u16* __restrict__ hout,
             float* __restrict__ xwout) {
  __shared__ float xt[64 * 257];
  __shared__ float smean[256], srstd[256];
  const int tid = threadIdx.x, lane = tid & 63, wv = tid >> 6;
  const int g = blockIdx.x;
  const int b = g / 196, rem = g % 196;
  const int wh = rem / 7, wg = rem % 7;
  const int base_r = b * 784 + wh * 28 + wg * 4;
  const int pr = tid >> 5, pc = tid & 31;
  int hp = wh * 8 + 4 + pr; if (hp >= 224) hp -= 224;
  int wp = wg * 32 + 4 + pc; if (wp >= 224) wp -= 224;
  const long roff = (long)b * 256 * 50176 + hp * 224 + wp;

  float s = 0.f, q = 0.f;
  for (int cc = 0; cc < 4; ++cc) {
#pragma unroll 8
    for (int i = 0; i < 64; ++i) {
      const int c = cc * 64 + i;
      const float v = x[(long)c * 50176 + roff];
      xt[i * 257 + tid] = v;
      s += v; q += v * v;
    }
    __syncthreads();
#pragma unroll 8
    for (int jj = 0; jj < 64; ++jj) {
      const int p = jj * 4 + wv;
      const int m = (base_r + ((p & 31) >> 3)) * 64 + (p >> 5) * 8 + (p & 7);
      xwout[(long)m * 256 + cc * 64 + lane] = xt[lane * 257 + p];
    }
    __syncthreads();
  }
  const float mean = s * (1.f / 256.f);
  smean[tid] = mean;
  srstd[tid] = rsqrtf(q * (1.f / 256.f) - mean * mean + 1e-5f);
  __syncthreads();

  float wr_[4], br_[4];
#pragma unroll
  for (int cc = 0; cc < 4; ++cc) { wr_[cc] = w1[cc * 64 + lane]; br_[cc] = b1[cc * 64 + lane]; }
#pragma unroll 2
  for (int jj = 0; jj < 64; ++jj) {
    const int p = jj * 4 + wv;
    const int m = (base_r + ((p & 31) >> 3)) * 64 + (p >> 5) * 8 + (p & 7);
    const float mu = smean[p], rs = srstd[p];
#pragma unroll
    for (int cc = 0; cc < 4; ++cc) {
      const float v = xwout[(long)m * 256 + cc * 64 + lane];
      hout[(long)m * 256 + cc * 64 + lane] = f2b((v - mu) * rs * wr_[cc] + br_[cc]);
    }
  }
}

// ---------- 256x256x(BK=64) bf16 GEMM, B given as [N][K], 8 waves (2x4) ----------
// 2-phase double-buffered global_load_lds staging, T2 k-slot XOR swizzle,
// 1-D grid with XCD chunk swizzle + column-fast decode.
// Operand-swapped MFMA (n in reg-dim) for all EPIs except v (EPI 5).
// EPI 0: q|k scatter, u16x4 along d          (NCOL=2, cols 0..511)
// EPI 5: v^T scatter, u16x4 along ii         (NCOL=1, col0=512)
// EPI 1: y += acc + bias (float4 RMW) + FUSED LN2 -> bout bf16 (NCOL=1)
// EPI 3: y += acc + bias (float4 RMW)        (NCOL=1)
// EPI 2: hidden = bf16(gelu(acc+b)), u16x4   (NCOL=4, ldc=1024)
template<int EPI, int NCOL>
__global__ __launch_bounds__(512, 2)
void gemm_bt(const u16* __restrict__ A, const u16* __restrict__ Bw, const int K,
             float* __restrict__ fout, const float* __restrict__ bias,
             u16* __restrict__ bout,
             const float* __restrict__ lnw, const float* __restrict__ lnb) {
  __shared__ __align__(16) u16 smem[65536];   // 128 KB
  u16* sA0 = smem;
  u16* sB0 = smem + 16384;
  u16* sA1 = smem + 32768;
  u16* sB1 = smem + 49152;

  const int tid  = threadIdx.x;
  const int lane = tid & 63;
  const int wid  = tid >> 6;       // 0..7
  const int wr   = wid >> 2;       // 0..1  (row half)
  const int wc   = wid & 3;        // 0..3  (col quarter)

  const int nwg = gridDim.x;
  const int bid = blockIdx.x;
  const int wg  = (bid & 7) * (nwg >> 3) + (bid >> 3);   // XCD chunk swizzle
  const int row_blk = wg / NCOL;                          // column-fast
  const int col_blk = wg - row_blk * NCOL;
  const int row0 = row_blk * 256;
  const int col0 = (EPI == 5) ? 512 : col_blk * 256;

  const f32x4 vzero = {0.f, 0.f, 0.f, 0.f};
  f32x4 acc[8][4];
#pragma unroll
  for (int i = 0; i < 8; ++i)
#pragma unroll
    for (int j = 0; j < 4; ++j) acc[i][j] = vzero;

  const int lrow = lane >> 3;
  const int lcol = ((lane & 7) << 3) ^ (lane & 56);  // pre-swizzled source k-offset
  const int l15  = lane & 15;
  const int l4   = lane >> 4;
  const int ksw  = (lane & 7) << 3;                  // ds_read swizzle

  const u16* pA = A  + (long)(row0 + lrow) * K + lcol;
  const u16* pB = Bw + (long)(col0 + lrow) * K + lcol;

#define STAGE_TILE(KT, DA, DB)                                       \
  {                                                                  \
    _Pragma("unroll")                                                \
    for (int ch = 0; ch < 4; ++ch) {                                 \
      const int rr = ch * 64 + wid * 8;                              \
      gload16(pA + (long)rr * K + (KT), (DA) + rr * 64);             \
      gload16(pB + (long)rr * K + (KT), (DB) + rr * 64);             \
    }                                                                \
  }

#define COMPUTE_TILE(SA, SB)                                                            \
  {                                                                                     \
    _Pragma("unroll")                                                                   \
    for (int kk = 0; kk < 2; ++kk) {                                                    \
      bf16x8 af[8], bfv[4];                                                             \
      _Pragma("unroll")                                                                 \
      for (int mi = 0; mi < 8; ++mi)                                                    \
        af[mi] = *(const bf16x8*)((SA) + (wr * 128 + mi * 16 + l15) * 64 +              \
                                  ((kk * 32 + l4 * 8) ^ ksw));                          \
      _Pragma("unroll")                                                                 \
      for (int nj = 0; nj < 4; ++nj)                                                    \
        bfv[nj] = *(const bf16x8*)((SB) + (wc * 64 + nj * 16 + l15) * 64 +              \
                                   ((kk * 32 + l4 * 8) ^ ksw));                         \
      _Pragma("unroll")                                                                 \
      for (int mi = 0; mi < 8; ++mi)                                                    \
        _Pragma("unroll")                                                               \
        for (int nj = 0; nj < 4; ++nj) {                                                \
          if (EPI == 5)                                                                 \
            acc[mi][nj] = __builtin_amdgcn_mfma_f32_16x16x32_bf16(af[mi], bfv[nj],      \
                                                                  acc[mi][nj], 0, 0, 0);\
          else                                                                          \
            acc[mi][nj] = __builtin_amdgcn_mfma_f32_16x16x32_bf16(bfv[nj], af[mi],      \
                                                                  acc[mi][nj], 0, 0, 0);\
        }                                                                               \
    }                                                                                   \
  }

  const int nt = K >> 6;
  STAGE_TILE(0, sA0, sB0);
  __syncthreads();
  for (int t = 0; t < nt; t += 2) {
    if (t + 1 < nt) STAGE_TILE((t + 1) << 6, sA1, sB1);
    COMPUTE_TILE(sA0, sB0);
    __syncthreads();
    if (t + 1 < nt) {
      if (t + 2 < nt) STAGE_TILE((t + 2) << 6, sA0, sB0);
      COMPUTE_TILE(sA1, sB1);
      __syncthreads();
    }
  }
#undef STAGE_TILE
#undef COMPUTE_TILE

  if (EPI == 0) {
    // q|k scatter, swapped orientation: lane=m, reg=n(d)
#pragma unroll
    for (int mi = 0; mi < 8; ++mi) {
      const int m = row0 + wr * 128 + mi * 16 + l15;
      const int rr = m >> 6, ii = m & 63;
#pragma unroll
      for (int nj = 0; nj < 4; ++nj) {
        const int n = col0 + wc * 64 + nj * 16 + (l4 << 2);
        const int s = n >> 8, hh = (n >> 5) & 7, d = n & 31;
        u16x4 p;
#pragma unroll
        for (int reg = 0; reg < 4; ++reg) p[reg] = f2b(acc[mi][nj][reg]);
        *(u16x4*)(bout + (long)s * 51380224L +
                  (long)((rr * 8 + hh) * 64 + ii) * 32 + d) = p;
      }
    }
  } else if (EPI == 5) {
    // v^T scatter, original orientation: lane=n(d), reg=m(ii)
#pragma unroll
    for (int mi = 0; mi < 8; ++mi) {
      const int mb = row0 + wr * 128 + mi * 16 + (l4 << 2);
      const int rrg = mb >> 6, ii = mb & 63;
#pragma unroll
      for (int nj = 0; nj < 4; ++nj) {
        const int n = 512 + wc * 64 + nj * 16 + l15;
        const int hh = (n >> 5) & 7, d = n & 31;
        u16x4 p;
#pragma unroll
        for (int reg = 0; reg < 4; ++reg) p[reg] = f2b(acc[mi][nj][reg]);
        *(u16x4*)(bout + 102760448L + (long)((rrg * 8 + hh) * 32 + d) * 64 + ii) = p;
      }
    }
  } else if (EPI == 1) {
    // y += acc + bias (float4 RMW), then fused LN2 -> bout (bf16 [m][256])
    f32x4 b4[4];
#pragma unroll
    for (int nj = 0; nj < 4; ++nj)
      b4[nj] = *(const f32x4*)(bias + wc * 64 + nj * 16 + (l4 << 2));
    float sS[8], sQ[8];
#pragma unroll
    for (int mi = 0; mi < 8; ++mi) {
      const int m = row0 + wr * 128 + mi * 16 + l15;
      float* yrow = fout + (long)m * 256;
      float s = 0.f, q = 0.f;
#pragma unroll
      for (int nj = 0; nj < 4; ++nj) {
        const int n = wc * 64 + nj * 16 + (l4 << 2);
        f32x4 o = *(f32x4*)(yrow + n);
#pragma unroll
        for (int reg = 0; reg < 4; ++reg) {
          o[reg] += acc[mi][nj][reg] + b4[nj][reg];
          s += o[reg]; q += o[reg] * o[reg];
        }
        *(f32x4*)(yrow + n) = o;
        acc[mi][nj] = o;
      }
      s += __shfl_xor(s, 16); s += __shfl_xor(s, 32);
      q += __shfl_xor(q, 16); q += __shfl_xor(q, 32);
      sS[mi] = s; sQ[mi] = q;
    }
    float* ps = (float*)smem;          // [2][8][16][4]
    float* pq = ps + 1024;
    if (lane < 16) {
#pragma unroll
      for (int mi = 0; mi < 8; ++mi) {
        const int idx = ((wr * 8 + mi) * 16 + l15) * 4 + wc;
        ps[idx] = sS[mi]; pq[idx] = sQ[mi];
      }
    }
    __syncthreads();
#pragma unroll
    for (int mi = 0; mi < 8; ++mi) {
      const int m = row0 + wr * 128 + mi * 16 + l15;
      const int base = ((wr * 8 + mi) * 16 + l15) * 4;
      const float S = ps[base] + ps[base + 1] + ps[base + 2] + ps[base + 3];
      const float Q = pq[base] + pq[base + 1] + pq[base + 2] + pq[base + 3];
      const float mean = S * (1.f / 256.f);
      const float rstd = rsqrtf(Q * (1.f / 256.f) - mean * mean + 1e-5f);
#pragma unroll
      for (int nj = 0; nj < 4; ++nj) {
        const int n = wc * 64 + nj * 16 + (l4 << 2);
        const f32x4 w4 = *(const f32x4*)(lnw + n);
        const f32x4 c4 = *(const f32x4*)(lnb + n);
        u16x4 p;
#pragma unroll
        for (int reg = 0; reg < 4; ++reg)
          p[reg] = f2b((acc[mi][nj][reg] - mean) * rstd * w4[reg] + c4[reg]);
        *(u16x4*)(bout + (long)m * 256 + n) = p;
      }
    }
  } else if (EPI == 3) {
    // y += acc + bias, float4 RMW (N=256, col0=0)
    f32x4 b4[4];
#pragma unroll
    for (int nj = 0; nj < 4; ++nj)
      b4[nj] = *(const f32x4*)(bias + wc * 64 + nj * 16 + (l4 << 2));
#pragma unroll
    for (int mi = 0; mi < 8; ++mi) {
      const int m = row0 + wr * 128 + mi * 16 + l15;
      float* yrow = fout + (long)m * 256;
#pragma unroll
      for (int nj = 0; nj < 4; ++nj) {
        const int n = wc * 64 + nj * 16 + (l4 << 2);
        f32x4 o = *(f32x4*)(yrow + n);
#pragma unroll
        for (int reg = 0; reg < 4; ++reg) o[reg] += acc[mi][nj][reg] + b4[nj][reg];
        *(f32x4*)(yrow + n) = o;
      }
    }
  } else {
    // EPI 2: hidden = bf16(gelu(acc+bias)), u16x4 along n, ldc=1024
    f32x4 b4[4];
#pragma unroll
    for (int nj = 0; nj < 4; ++nj)
      b4[nj] = *(const f32x4*)(bias + col0 + wc * 64 + nj * 16 + (l4 << 2));
#pragma unroll
    for (int mi = 0; mi < 8; ++mi) {
      const int m = row0 + wr * 128 + mi * 16 + l15;
#pragma unroll
      for (int nj = 0; nj < 4; ++nj) {
        const int n = col0 + wc * 64 + nj * 16 + (l4 << 2);
        u16x4 p;
#pragma unroll
        for (int reg = 0; reg < 4; ++reg)
          p[reg] = f2b(gelu_fast(acc[mi][nj][reg] + b4[nj][reg]));
        *(u16x4*)(bout + (long)m * 1024 + n) = p;
      }
    }
  }
}

// ---------- per-window attention: 1 wave = 1 head ----------
// P stored bf16 in per-wave LDS (8 KB) with XOR swizzle j ^= (i&7)<<3.
// PV computed operand-swapped: O^T = mfma(V^T, P) -> u16x4 stores along d.
__global__ __launch_bounds__(256)
void attn_win(const u16* __restrict__ qkv, const float* __restrict__ rpb,
              u16* __restrict__ aout) {
  __shared__ u16 Pl[4][4096];
  __shared__ float srpb[1800];
  const int tid = threadIdx.x, lane = tid & 63, wv = tid >> 6;
  const int bid = blockIdx.x;
  const int r = bid >> 1;
  const int h = (bid & 1) * 4 + wv;
  for (int i = tid; i < 1800; i += 256) srpb[i] = rpb[i];
  __syncthreads();

  // reference quirk: jnp.repeat(mask, B, axis=0) -> window r uses mask[r/4]
  const int midx = r >> 2;
  const int wh = midx / 28, ww = midx % 28;
  const int l15 = lane & 15, l4 = lane >> 4;

  u16* Pw = &Pl[wv][0];
  const long hb = (long)(r * 8 + h) * 2048;
  const u16* qh = qkv + hb;
  const u16* kh = qkv + 51380224 + hb;
  const u16* vh = qkv + 102760448 + hb;

  int rj[4], cj[4], labj[4];
#pragma unroll
  for (int nj = 0; nj < 4; ++nj) {
    const int j = nj * 16 + l15;
    rj[nj] = j >> 3; cj[nj] = j & 7;
    const int hp = wh * 8 + rj[nj], wp = ww * 8 + cj[nj];
    const int lh = (hp < 216) ? 0 : ((hp < 220) ? 1 : 2);
    const int lw = (wp < 216) ? 0 : ((wp < 220) ? 1 : 2);
    labj[nj] = lh * 3 + lw;
  }

  const f32x4 vzero = {0.f, 0.f, 0.f, 0.f};

  bf16x8 qf[4], kf[4];
#pragma unroll
  for (int mi = 0; mi < 4; ++mi)
    qf[mi] = *(const bf16x8*)(qh + (mi * 16 + l15) * 32 + l4 * 8);
#pragma unroll
  for (int nj = 0; nj < 4; ++nj)
    kf[nj] = *(const bf16x8*)(kh + (nj * 16 + l15) * 32 + l4 * 8);

  f32x4 S[4][4];
#pragma unroll
  for (int mi = 0; mi < 4; ++mi)
#pragma unroll
    for (int nj = 0; nj < 4; ++nj)
      S[mi][nj] = __builtin_amdgcn_mfma_f32_16x16x32_bf16(qf[mi], kf[nj], vzero, 0, 0, 0);

  // softmax (row-parallel over 16-lane groups) + normalized bf16 P -> LDS
#pragma unroll
  for (int mi = 0; mi < 4; ++mi)
#pragma unroll
    for (int reg = 0; reg < 4; ++reg) {
      const int i = mi * 16 + (l4 << 2) + reg;
      const int ri = i >> 3, ci = i & 7;
      const int hp = wh * 8 + ri, wp = ww * 8 + ci;
      const int lh = (hp < 216) ? 0 : ((hp < 220) ? 1 : 2);
      const int lw = (wp < 216) ? 0 : ((wp < 220) ? 1 : 2);
      const int li = lh * 3 + lw;
      float v[4];
#pragma unroll
      for (int nj = 0; nj < 4; ++nj) {
        const int idx = (ri - rj[nj] + 7) * 15 + (ci - cj[nj] + 7);
        v[nj] = S[mi][nj][reg] * 0.17677669529663687f + srpb[idx * 8 + h]
              + ((li != labj[nj]) ? -100.0f : 0.0f);
      }
      float mx = fmaxf(fmaxf(v[0], v[1]), fmaxf(v[2], v[3]));
      mx = fmaxf(mx, __shfl_xor(mx, 1));
      mx = fmaxf(mx, __shfl_xor(mx, 2));
      mx = fmaxf(mx, __shfl_xor(mx, 4));
      mx = fmaxf(mx, __shfl_xor(mx, 8));
      float sum = 0.f;
#pragma unroll
      for (int nj = 0; nj < 4; ++nj) { v[nj] = __expf(v[nj] - mx); sum += v[nj]; }
      sum += __shfl_xor(sum, 1);
      sum += __shfl_xor(sum, 2);
      sum += __shfl_xor(sum, 4);
      sum += __shfl_xor(sum, 8);
      const float rinv = __builtin_amdgcn_rcpf(sum);
      const int sw = (i & 7) << 3;
#pragma unroll
      for (int nj = 0; nj < 4; ++nj)
        Pw[i * 64 + ((nj * 16 + l15) ^ sw)] = f2b(v[nj] * rinv);
    }

  // PV: O^T = mfma(V^T, P) — per-wave LDS, no barrier needed
  f32x4 OT[2][4];
#pragma unroll
  for (int td = 0; td < 2; ++td)
#pragma unroll
    for (int ti = 0; ti < 4; ++ti) OT[td][ti] = vzero;

  const int rsw = (l15 & 7) << 3;
#pragma unroll
  for (int kk = 0; kk < 2; ++kk) {
    bf16x8 pf[4], vf[2];
#pragma unroll
    for (int ti = 0; ti < 4; ++ti)
      pf[ti] = *(const bf16x8*)(Pw + (ti * 16 + l15) * 64 + ((kk * 32 + l4 * 8) ^ rsw));
#pragma unroll
    for (int td = 0; td < 2; ++td)
      vf[td] = *(const bf16x8*)(vh + (td * 16 + l15) * 64 + kk * 32 + l4 * 8);
#pragma unroll
    for (int td = 0; td < 2; ++td)
#pragma unroll
      for (int ti = 0; ti < 4; ++ti)
        OT[td][ti] = __builtin_amdgcn_mfma_f32_16x16x32_bf16(vf[td], pf[ti], OT[td][ti], 0, 0, 0);
  }

  // write: lane holds O[i=ti*16+l15][d=td*16+4*l4+reg] -> u16x4 along d
#pragma unroll
  for (int td = 0; td < 2; ++td)
#pragma unroll
    for (int ti = 0; ti < 4; ++ti) {
      const int i = ti * 16 + l15;
      const int d0 = td * 16 + (l4 << 2);
      u16x4 p;
#pragma unroll
      for (int reg = 0; reg < 4; ++reg) p[reg] = f2b(OT[td][ti][reg]);
      *(u16x4*)(aout + (long)(r * 64 + i) * 256 + h * 32 + d0) = p;
    }
}

// ---------- un-window scatter, 4 adjacent windows per block ----------
__global__ __launch_bounds__(256)
void unwin(const float* __restrict__ y, float* __restrict__ out) {
  __shared__ float xt[64 * 257];
  const int tid = threadIdx.x, lane = tid & 63, wv = tid >> 6;
  const int g = blockIdx.x;
  const int b = g / 196, rem = g % 196;
  const int wh = rem / 7, wg = rem % 7;
  const int base_r = b * 784 + wh * 28 + wg * 4;
  const int pr = tid >> 5, pc = tid & 31;
  int hp = wh * 8 + 4 + pr; if (hp >= 224) hp -= 224;
  int wp = wg * 32 + 4 + pc; if (wp >= 224) wp -= 224;
  const long woff = (long)b * 256 * 50176 + hp * 224 + wp;

  for (int cc = 0; cc < 4; ++cc) {
#pragma unroll 8
    for (int jj = 0; jj < 64; ++jj) {
      const int p = jj * 4 + wv;
      const int m = (base_r + ((p & 31) >> 3)) * 64 + (p >> 5) * 8 + (p & 7);
      xt[lane * 257 + p] = y[(long)m * 256 + cc * 64 + lane];
    }
    __syncthreads();
#pragma unroll 8
    for (int i = 0; i < 64; ++i)
      out[(long)(cc * 64 + i) * 50176 + woff] = xt[i * 257 + tid];
    __syncthreads();
  }
}

// ---------- launch ----------
extern "C" void kernel_launch(void* const* d_in, const int* in_sizes, int n_in,
                              void* d_out, int out_size, void* d_ws, size_t ws_size,
                              hipStream_t stream) {
  (void)in_sizes; (void)n_in; (void)out_size; (void)ws_size;
  const float* x     = (const float*)d_in[0];
  const float* qkvw  = (const float*)d_in[1];
  const float* projw = (const float*)d_in[2];
  const float* projb = (const float*)d_in[3];
  const float* rpb   = (const float*)d_in[4];
  const float* n1w   = (const float*)d_in[5];
  const float* n1b   = (const float*)d_in[6];
  const float* n2w   = (const float*)d_in[7];
  const float* n2b   = (const float*)d_in[8];
  const float* w1    = (const float*)d_in[9];
  const float* b1    = (const float*)d_in[10];
  const float* w2    = (const float*)d_in[11];
  const float* b2    = (const float*)d_in[12];

  char* ws = (char*)d_ws;
  u16*   hbuf   = (u16*)(ws);                  // 102,760,448 B : h, later h2
  u16*   qkvb   = (u16*)(ws + 102760448);      // 308,281,344 B : q|k|v
  u16*   abuf   = (u16*)(ws + 411041792);      // 102,760,448 B : attn out
  float* ybuf   = (float*)(ws + 513802240);    // 205,520,896 B : fp32 residual stream
  u16*   hidb   = (u16*)(ws + 102760448);      // 411,041,792 B : overlays qkv+attn (dead by then)
  u16*   qkvwb  = (u16*)(ws + 719323136);
  u16*   projwb = (u16*)(ws + 719716352);
  u16*   w1b    = (u16*)(ws + 719847424);
  u16*   w2b    = (u16*)(ws + 720371712);      // end: 720,896,000 B

  conv_weights<<<3072, 256, 0, stream>>>(qkvw, projw, w1, w2, qkvwb, projwb, w1b, w2b);
  ln1_win<<<784, 256, 0, stream>>>(x, n1w, n1b, hbuf, ybuf);
  gemm_bt<0, 2><<<1568, 512, 0, stream>>>(hbuf, qkvwb, 256, nullptr, nullptr, qkvb, nullptr, nullptr);
  gemm_bt<5, 1><<<784, 512, 0, stream>>>(hbuf, qkvwb, 256, nullptr, nullptr, qkvb, nullptr, nullptr);
  attn_win<<<6272, 256, 0, stream>>>(qkvb, rpb, abuf);
  gemm_bt<1, 1><<<784, 512, 0, stream>>>(abuf, projwb, 256, ybuf, projb, hbuf, n2w, n2b);
  gemm_bt<2, 4><<<3136, 512, 0, stream>>>(hbuf, w1b, 256, nullptr, b1, hidb, nullptr, nullptr);
  gemm_bt<3, 1><<<784, 512, 0, stream>>>(hidb, w2b, 1024, ybuf, b2, nullptr, nullptr, nullptr);
  unwin<<<784, 256, 0, stream>>>(ybuf, (float*)d_out);
}

// Round 7
// 1243.882 us; speedup vs baseline: 1.4072x; 1.0103x over previous
//
#include <hip/hip_runtime.h>

typedef unsigned short u16;
typedef unsigned int   u32;
typedef __attribute__((ext_vector_type(8))) __bf16 bf16x8;
typedef __attribute__((ext_vector_type(4))) float  f32x4;
typedef __attribute__((ext_vector_type(4))) u16    u16x4;
typedef __attribute__((ext_vector_type(8))) u16    u16x8;

#define DEV __device__ __forceinline__

// ---------- helpers ----------
DEV u16 f2b(float f) {               // fp32 -> bf16 bits, RNE
  union { float f; u32 u; } a; a.f = f;
  const u32 u = a.u;
  return (u16)((u + 0x7fffu + ((u >> 16) & 1u)) >> 16);
}

// tanh-form GELU as x*sigmoid(1.5957691*(x+0.044715 x^3)); exp2-folded.
DEV float gelu_fast(float x) {
  const float x2 = x * x;
  const float t  = __builtin_fmaf(0.1029430f, x2, 2.3022150f);  // *log2(e) folded
  const float e  = __builtin_exp2f(x * t);
  const float r  = __builtin_amdgcn_rcpf(1.0f + e);
  return __builtin_fmaf(-x, r, x);   // x - x/(1+e) = x*sigmoid(z)
}

DEV void gload16(const void* g, void* l) {
  __builtin_amdgcn_global_load_lds(
      (const __attribute__((address_space(1))) void*)g,
      (__attribute__((address_space(3))) void*)l, 16, 0, 0);
}

// ---------- weight conversion (fp32 -> bf16) ----------
__global__ __launch_bounds__(256)
void conv_weights(const float* __restrict__ qkvw, const float* __restrict__ projw,
                  const float* __restrict__ w1,   const float* __restrict__ w2,
                  u16* __restrict__ dq, u16* __restrict__ dp,
                  u16* __restrict__ d1, u16* __restrict__ d2) {
  const int t = blockIdx.x * 256 + threadIdx.x;
  if (t < 196608)      dq[t]          = f2b(qkvw[t]);
  else if (t < 262144) dp[t - 196608] = f2b(projw[t - 196608]);
  else if (t < 524288) d1[t - 262144] = f2b(w1[t - 262144]);
  else                 d2[t - 524288] = f2b(w2[t - 524288]);
}

// ---------- window gather + LN1, 4 adjacent windows per block ----------
__global__ __launch_bounds__(256)
void ln1_win(const float* __restrict__ x, const float* __restrict__ w1,
             const float* __restrict__ b1, u16* __restrict__ hout,
             float* __restrict__ xwout) {
  __shared__ float xt[64 * 257];
  __shared__ float smean[256], srstd[256];
  const int tid = threadIdx.x, lane = tid & 63, wv = tid >> 6;
  const int g = blockIdx.x;
  const int b = g / 196, rem = g % 196;
  const int wh = rem / 7, wg = rem % 7;
  const int base_r = b * 784 + wh * 28 + wg * 4;
  const int pr = tid >> 5, pc = tid & 31;
  int hp = wh * 8 + 4 + pr; if (hp >= 224) hp -= 224;
  int wp = wg * 32 + 4 + pc; if (wp >= 224) wp -= 224;
  const long roff = (long)b * 256 * 50176 + hp * 224 + wp;

  float s = 0.f, q = 0.f;
  for (int cc = 0; cc < 4; ++cc) {
#pragma unroll 8
    for (int i = 0; i < 64; ++i) {
      const int c = cc * 64 + i;
      const float v = x[(long)c * 50176 + roff];
      xt[i * 257 + tid] = v;
      s += v; q += v * v;
    }
    __syncthreads();
#pragma unroll 8
    for (int jj = 0; jj < 64; ++jj) {
      const int p = jj * 4 + wv;
      const int m = (base_r + ((p & 31) >> 3)) * 64 + (p >> 5) * 8 + (p & 7);
      xwout[(long)m * 256 + cc * 64 + lane] = xt[lane * 257 + p];
    }
    __syncthreads();
  }
  const float mean = s * (1.f / 256.f);
  smean[tid] = mean;
  srstd[tid] = rsqrtf(q * (1.f / 256.f) - mean * mean + 1e-5f);
  __syncthreads();

  float wr_[4], br_[4];
#pragma unroll
  for (int cc = 0; cc < 4; ++cc) { wr_[cc] = w1[cc * 64 + lane]; br_[cc] = b1[cc * 64 + lane]; }
#pragma unroll 2
  for (int jj = 0; jj < 64; ++jj) {
    const int p = jj * 4 + wv;
    const int m = (base_r + ((p & 31) >> 3)) * 64 + (p >> 5) * 8 + (p & 7);
    const float mu = smean[p], rs = srstd[p];
#pragma unroll
    for (int cc = 0; cc < 4; ++cc) {
      const float v = xwout[(long)m * 256 + cc * 64 + lane];
      hout[(long)m * 256 + cc * 64 + lane] = f2b((v - mu) * rs * wr_[cc] + br_[cc]);
    }
  }
}

// ---------- 256x256x(BK=64) bf16 GEMM, B given as [N][K], 8 waves (2x4) ----------
// 2-phase double-buffer with COUNTED vmcnt (T4): next tile's 8 loads stay in
// flight across the barrier; wait vmcnt(8) releases when current tile is
// resident. Raw s_barrier (no drain). T2 k-slot XOR swizzle, XCD chunk
// swizzle, column-fast decode. Operand-swapped MFMA except v sub-pass.
// EPI 0: qkv (NCOL=3): col_blk<2 -> q|k u16x4 along d; col_blk==2 -> v^T
// EPI 1: y += acc + bias (float4 RMW) + FUSED LN2 -> bout bf16 (NCOL=1)
// EPI 3: y += acc + bias (float4 RMW)        (NCOL=1)
// EPI 2: hidden = bf16(gelu(acc+b)), u16x4   (NCOL=4, ldc=1024)
template<int EPI, int NCOL>
__global__ __launch_bounds__(512, 2)
void gemm_bt(const u16* __restrict__ A, const u16* __restrict__ Bw, const int K,
             float* __restrict__ fout, const float* __restrict__ bias,
             u16* __restrict__ bout,
             const float* __restrict__ lnw, const float* __restrict__ lnb) {
  __shared__ __align__(16) u16 smem[65536];   // 128 KB
  u16* sA0 = smem;
  u16* sB0 = smem + 16384;
  u16* sA1 = smem + 32768;
  u16* sB1 = smem + 49152;

  const int tid  = threadIdx.x;
  const int lane = tid & 63;
  const int wid  = tid >> 6;       // 0..7
  const int wr   = wid >> 2;       // 0..1  (row half)
  const int wc   = wid & 3;        // 0..3  (col quarter)

  const int nwg = gridDim.x;
  const int bid = blockIdx.x;
  const int wg  = (bid & 7) * (nwg >> 3) + (bid >> 3);   // XCD chunk swizzle
  const int row_blk = wg / NCOL;                          // column-fast
  const int col_blk = wg - row_blk * NCOL;
  const int row0 = row_blk * 256;
  const int col0 = col_blk * 256;

  const f32x4 vzero = {0.f, 0.f, 0.f, 0.f};
  f32x4 acc[8][4];
#pragma unroll
  for (int i = 0; i < 8; ++i)
#pragma unroll
    for (int j = 0; j < 4; ++j) acc[i][j] = vzero;

  const int lrow = lane >> 3;
  const int lcol = ((lane & 7) << 3) ^ (lane & 56);  // pre-swizzled source k-offset
  const int l15  = lane & 15;
  const int l4   = lane >> 4;
  const int ksw  = (lane & 7) << 3;                  // ds_read swizzle

  const u16* pA = A  + (long)(row0 + lrow) * K + lcol;
  const u16* pB = Bw + (long)(col0 + lrow) * K + lcol;

#define STAGE_TILE(KT, DA, DB)                                       \
  {                                                                  \
    _Pragma("unroll")                                                \
    for (int ch = 0; ch < 4; ++ch) {                                 \
      const int rr = ch * 64 + wid * 8;                              \
      gload16(pA + (long)rr * K + (KT), (DA) + rr * 64);             \
      gload16(pB + (long)rr * K + (KT), (DB) + rr * 64);             \
    }                                                                \
  }

#define COMPUTE_TILE(SA, SB, SWAP)                                                      \
  {                                                                                     \
    _Pragma("unroll")                                                                   \
    for (int kk = 0; kk < 2; ++kk) {                                                    \
      bf16x8 af[8], bfv[4];                                                             \
      _Pragma("unroll")                                                                 \
      for (int mi = 0; mi < 8; ++mi)                                                    \
        af[mi] = *(const bf16x8*)((SA) + (wr * 128 + mi * 16 + l15) * 64 +              \
                                  ((kk * 32 + l4 * 8) ^ ksw));                          \
      _Pragma("unroll")                                                                 \
      for (int nj = 0; nj < 4; ++nj)                                                    \
        bfv[nj] = *(const bf16x8*)((SB) + (wc * 64 + nj * 16 + l15) * 64 +              \
                                   ((kk * 32 + l4 * 8) ^ ksw));                         \
      _Pragma("unroll")                                                                 \
      for (int mi = 0; mi < 8; ++mi)                                                    \
        _Pragma("unroll")                                                               \
        for (int nj = 0; nj < 4; ++nj) {                                                \
          if (SWAP)                                                                     \
            acc[mi][nj] = __builtin_amdgcn_mfma_f32_16x16x32_bf16(bfv[nj], af[mi],      \
                                                                  acc[mi][nj], 0, 0, 0);\
          else                                                                          \
            acc[mi][nj] = __builtin_amdgcn_mfma_f32_16x16x32_bf16(af[mi], bfv[nj],      \
                                                                  acc[mi][nj], 0, 0, 0);\
        }                                                                               \
    }                                                                                   \
  }

// counted-vmcnt 2-phase k-loop: one STAGE = 8 per-thread loads -> vmcnt(8)
#define KLOOP(SWAP)                                                  \
  {                                                                  \
    const int nt = K >> 6;                                           \
    STAGE_TILE(0, sA0, sB0);                                         \
    int cur = 0;                                                     \
    for (int t = 0; t < nt; ++t) {                                   \
      u16* cA = cur ? sA1 : sA0;                                     \
      u16* cB = cur ? sB1 : sB0;                                     \
      u16* nA = cur ? sA0 : sA1;                                     \
      u16* nB = cur ? sB0 : sB1;                                     \
      if (t + 1 < nt) {                                              \
        STAGE_TILE((t + 1) << 6, nA, nB);                            \
        asm volatile("s_waitcnt vmcnt(8)" ::: "memory");             \
      } else {                                                       \
        asm volatile("s_waitcnt vmcnt(0)" ::: "memory");             \
      }                                                              \
      __builtin_amdgcn_s_barrier();                                  \
      asm volatile("" ::: "memory");                                 \
      COMPUTE_TILE(cA, cB, SWAP);                                    \
      asm volatile("" ::: "memory");                                 \
      __builtin_amdgcn_s_barrier();                                  \
      cur ^= 1;                                                      \
    }                                                                \
  }

  if (EPI == 0 && col_blk == 2) {
    // ---- v: unswapped orientation, v^T scatter (lane=n(d), reg=m(ii)) ----
    KLOOP(0);
#pragma unroll
    for (int mi = 0; mi < 8; ++mi) {
      const int mb = row0 + wr * 128 + mi * 16 + (l4 << 2);
      const int rrg = mb >> 6, ii = mb & 63;
#pragma unroll
      for (int nj = 0; nj < 4; ++nj) {
        const int n = 512 + wc * 64 + nj * 16 + l15;
        const int hh = (n >> 5) & 7, d = n & 31;
        u16x4 p;
#pragma unroll
        for (int reg = 0; reg < 4; ++reg) p[reg] = f2b(acc[mi][nj][reg]);
        *(u16x4*)(bout + 102760448L + (long)((rrg * 8 + hh) * 32 + d) * 64 + ii) = p;
      }
    }
    return;
  }

  KLOOP(1);

#undef STAGE_TILE
#undef COMPUTE_TILE
#undef KLOOP

  if (EPI == 0) {
    // q|k scatter, swapped orientation: lane=m, reg=n(d)
#pragma unroll
    for (int mi = 0; mi < 8; ++mi) {
      const int m = row0 + wr * 128 + mi * 16 + l15;
      const int rr = m >> 6, ii = m & 63;
#pragma unroll
      for (int nj = 0; nj < 4; ++nj) {
        const int n = col0 + wc * 64 + nj * 16 + (l4 << 2);
        const int s = n >> 8, hh = (n >> 5) & 7, d = n & 31;
        u16x4 p;
#pragma unroll
        for (int reg = 0; reg < 4; ++reg) p[reg] = f2b(acc[mi][nj][reg]);
        *(u16x4*)(bout + (long)s * 51380224L +
                  (long)((rr * 8 + hh) * 64 + ii) * 32 + d) = p;
      }
    }
  } else if (EPI == 1) {
    // y += acc + bias (float4 RMW), then fused LN2 -> bout (bf16 [m][256])
    f32x4 b4[4];
#pragma unroll
    for (int nj = 0; nj < 4; ++nj)
      b4[nj] = *(const f32x4*)(bias + wc * 64 + nj * 16 + (l4 << 2));
    float sS[8], sQ[8];
#pragma unroll
    for (int mi = 0; mi < 8; ++mi) {
      const int m = row0 + wr * 128 + mi * 16 + l15;
      float* yrow = fout + (long)m * 256;
      float s = 0.f, q = 0.f;
#pragma unroll
      for (int nj = 0; nj < 4; ++nj) {
        const int n = wc * 64 + nj * 16 + (l4 << 2);
        f32x4 o = *(f32x4*)(yrow + n);
#pragma unroll
        for (int reg = 0; reg < 4; ++reg) {
          o[reg] += acc[mi][nj][reg] + b4[nj][reg];
          s += o[reg]; q += o[reg] * o[reg];
        }
        *(f32x4*)(yrow + n) = o;
        acc[mi][nj] = o;
      }
      s += __shfl_xor(s, 16); s += __shfl_xor(s, 32);
      q += __shfl_xor(q, 16); q += __shfl_xor(q, 32);
      sS[mi] = s; sQ[mi] = q;
    }
    float* ps = (float*)smem;          // [2][8][16][4]
    float* pq = ps + 1024;
    __syncthreads();
    if (lane < 16) {
#pragma unroll
      for (int mi = 0; mi < 8; ++mi) {
        const int idx = ((wr * 8 + mi) * 16 + l15) * 4 + wc;
        ps[idx] = sS[mi]; pq[idx] = sQ[mi];
      }
    }
    __syncthreads();
#pragma unroll
    for (int mi = 0; mi < 8; ++mi) {
      const int m = row0 + wr * 128 + mi * 16 + l15;
      const int base = ((wr * 8 + mi) * 16 + l15) * 4;
      const float S = ps[base] + ps[base + 1] + ps[base + 2] + ps[base + 3];
      const float Q = pq[base] + pq[base + 1] + pq[base + 2] + pq[base + 3];
      const float mean = S * (1.f / 256.f);
      const float rstd = rsqrtf(Q * (1.f / 256.f) - mean * mean + 1e-5f);
#pragma unroll
      for (int nj = 0; nj < 4; ++nj) {
        const int n = wc * 64 + nj * 16 + (l4 << 2);
        const f32x4 w4 = *(const f32x4*)(lnw + n);
        const f32x4 c4 = *(const f32x4*)(lnb + n);
        u16x4 p;
#pragma unroll
        for (int reg = 0; reg < 4; ++reg)
          p[reg] = f2b((acc[mi][nj][reg] - mean) * rstd * w4[reg] + c4[reg]);
        *(u16x4*)(bout + (long)m * 256 + n) = p;
      }
    }
  } else if (EPI == 3) {
    // y += acc + bias, float4 RMW (N=256, col0=0)
    f32x4 b4[4];
#pragma unroll
    for (int nj = 0; nj < 4; ++nj)
      b4[nj] = *(const f32x4*)(bias + wc * 64 + nj * 16 + (l4 << 2));
#pragma unroll
    for (int mi = 0; mi < 8; ++mi) {
      const int m = row0 + wr * 128 + mi * 16 + l15;
      float* yrow = fout + (long)m * 256;
#pragma unroll
      for (int nj = 0; nj < 4; ++nj) {
        const int n = wc * 64 + nj * 16 + (l4 << 2);
        f32x4 o = *(f32x4*)(yrow + n);
#pragma unroll
        for (int reg = 0; reg < 4; ++reg) o[reg] += acc[mi][nj][reg] + b4[nj][reg];
        *(f32x4*)(yrow + n) = o;
      }
    }
  } else if (EPI == 2) {
    // hidden = bf16(gelu(acc+bias)), u16x4 along n, ldc=1024
    f32x4 b4[4];
#pragma unroll
    for (int nj = 0; nj < 4; ++nj)
      b4[nj] = *(const f32x4*)(bias + col0 + wc * 64 + nj * 16 + (l4 << 2));
#pragma unroll
    for (int mi = 0; mi < 8; ++mi) {
      const int m = row0 + wr * 128 + mi * 16 + l15;
#pragma unroll
      for (int nj = 0; nj < 4; ++nj) {
        const int n = col0 + wc * 64 + nj * 16 + (l4 << 2);
        u16x4 p;
#pragma unroll
        for (int reg = 0; reg < 4; ++reg)
          p[reg] = f2b(gelu_fast(acc[mi][nj][reg] + b4[nj][reg]));
        *(u16x4*)(bout + (long)m * 1024 + n) = p;
      }
    }
  }
}

// ---------- per-window attention: 1 wave = 1 head ----------
// P stored bf16 in per-wave LDS (8 KB) with XOR swizzle j ^= (i&7)<<3.
// PV computed operand-swapped: O^T = mfma(V^T, P) -> u16x4 stores along d.
__global__ __launch_bounds__(256)
void attn_win(const u16* __restrict__ qkv, const float* __restrict__ rpb,
              u16* __restrict__ aout) {
  __shared__ u16 Pl[4][4096];
  __shared__ float srpb[1800];
  const int tid = threadIdx.x, lane = tid & 63, wv = tid >> 6;
  const int bid = blockIdx.x;
  const int r = bid >> 1;
  const int h = (bid & 1) * 4 + wv;
  for (int i = tid; i < 1800; i += 256) srpb[i] = rpb[i];
  __syncthreads();

  // reference quirk: jnp.repeat(mask, B, axis=0) -> window r uses mask[r/4]
  const int midx = r >> 2;
  const int wh = midx / 28, ww = midx % 28;
  const int l15 = lane & 15, l4 = lane >> 4;

  u16* Pw = &Pl[wv][0];
  const long hb = (long)(r * 8 + h) * 2048;
  const u16* qh = qkv + hb;
  const u16* kh = qkv + 51380224 + hb;
  const u16* vh = qkv + 102760448 + hb;

  int rj[4], cj[4], labj[4];
#pragma unroll
  for (int nj = 0; nj < 4; ++nj) {
    const int j = nj * 16 + l15;
    rj[nj] = j >> 3; cj[nj] = j & 7;
    const int hp = wh * 8 + rj[nj], wp = ww * 8 + cj[nj];
    const int lh = (hp < 216) ? 0 : ((hp < 220) ? 1 : 2);
    const int lw = (wp < 216) ? 0 : ((wp < 220) ? 1 : 2);
    labj[nj] = lh * 3 + lw;
  }

  const f32x4 vzero = {0.f, 0.f, 0.f, 0.f};

  bf16x8 qf[4], kf[4];
#pragma unroll
  for (int mi = 0; mi < 4; ++mi)
    qf[mi] = *(const bf16x8*)(qh + (mi * 16 + l15) * 32 + l4 * 8);
#pragma unroll
  for (int nj = 0; nj < 4; ++nj)
    kf[nj] = *(const bf16x8*)(kh + (nj * 16 + l15) * 32 + l4 * 8);

  f32x4 S[4][4];
#pragma unroll
  for (int mi = 0; mi < 4; ++mi)
#pragma unroll
    for (int nj = 0; nj < 4; ++nj)
      S[mi][nj] = __builtin_amdgcn_mfma_f32_16x16x32_bf16(qf[mi], kf[nj], vzero, 0, 0, 0);

  // softmax (row-parallel over 16-lane groups) + normalized bf16 P -> LDS
#pragma unroll
  for (int mi = 0; mi < 4; ++mi)
#pragma unroll
    for (int reg = 0; reg < 4; ++reg) {
      const int i = mi * 16 + (l4 << 2) + reg;
      const int ri = i >> 3, ci = i & 7;
      const int hp = wh * 8 + ri, wp = ww * 8 + ci;
      const int lh = (hp < 216) ? 0 : ((hp < 220) ? 1 : 2);
      const int lw = (wp < 216) ? 0 : ((wp < 220) ? 1 : 2);
      const int li = lh * 3 + lw;
      float v[4];
#pragma unroll
      for (int nj = 0; nj < 4; ++nj) {
        const int idx = (ri - rj[nj] + 7) * 15 + (ci - cj[nj] + 7);
        v[nj] = S[mi][nj][reg] * 0.17677669529663687f + srpb[idx * 8 + h]
              + ((li != labj[nj]) ? -100.0f : 0.0f);
      }
      float mx = fmaxf(fmaxf(v[0], v[1]), fmaxf(v[2], v[3]));
      mx = fmaxf(mx, __shfl_xor(mx, 1));
      mx = fmaxf(mx, __shfl_xor(mx, 2));
      mx = fmaxf(mx, __shfl_xor(mx, 4));
      mx = fmaxf(mx, __shfl_xor(mx, 8));
      float sum = 0.f;
#pragma unroll
      for (int nj = 0; nj < 4; ++nj) { v[nj] = __expf(v[nj] - mx); sum += v[nj]; }
      sum += __shfl_xor(sum, 1);
      sum += __shfl_xor(sum, 2);
      sum += __shfl_xor(sum, 4);
      sum += __shfl_xor(sum, 8);
      const float rinv = __builtin_amdgcn_rcpf(sum);
      const int sw = (i & 7) << 3;
#pragma unroll
      for (int nj = 0; nj < 4; ++nj)
        Pw[i * 64 + ((nj * 16 + l15) ^ sw)] = f2b(v[nj] * rinv);
    }

  // PV: O^T = mfma(V^T, P) — per-wave LDS, no barrier needed
  f32x4 OT[2][4];
#pragma unroll
  for (int td = 0; td < 2; ++td)
#pragma unroll
    for (int ti = 0; ti < 4; ++ti) OT[td][ti] = vzero;

  const int rsw = (l15 & 7) << 3;
#pragma unroll
  for (int kk = 0; kk < 2; ++kk) {
    bf16x8 pf[4], vf[2];
#pragma unroll
    for (int ti = 0; ti < 4; ++ti)
      pf[ti] = *(const bf16x8*)(Pw + (ti * 16 + l15) * 64 + ((kk * 32 + l4 * 8) ^ rsw));
#pragma unroll
    for (int td = 0; td < 2; ++td)
      vf[td] = *(const bf16x8*)(vh + (td * 16 + l15) * 64 + kk * 32 + l4 * 8);
#pragma unroll
    for (int td = 0; td < 2; ++td)
#pragma unroll
      for (int ti = 0; ti < 4; ++ti)
        OT[td][ti] = __builtin_amdgcn_mfma_f32_16x16x32_bf16(vf[td], pf[ti], OT[td][ti], 0, 0, 0);
  }

  // write: lane holds O[i=ti*16+l15][d=td*16+4*l4+reg] -> u16x4 along d
#pragma unroll
  for (int td = 0; td < 2; ++td)
#pragma unroll
    for (int ti = 0; ti < 4; ++ti) {
      const int i = ti * 16 + l15;
      const int d0 = td * 16 + (l4 << 2);
      u16x4 p;
#pragma unroll
      for (int reg = 0; reg < 4; ++reg) p[reg] = f2b(OT[td][ti][reg]);
      *(u16x4*)(aout + (long)(r * 64 + i) * 256 + h * 32 + d0) = p;
    }
}

// ---------- un-window scatter, 4 adjacent windows per block ----------
__global__ __launch_bounds__(256)
void unwin(const float* __restrict__ y, float* __restrict__ out) {
  __shared__ float xt[64 * 257];
  const int tid = threadIdx.x, lane = tid & 63, wv = tid >> 6;
  const int g = blockIdx.x;
  const int b = g / 196, rem = g % 196;
  const int wh = rem / 7, wg = rem % 7;
  const int base_r = b * 784 + wh * 28 + wg * 4;
  const int pr = tid >> 5, pc = tid & 31;
  int hp = wh * 8 + 4 + pr; if (hp >= 224) hp -= 224;
  int wp = wg * 32 + 4 + pc; if (wp >= 224) wp -= 224;
  const long woff = (long)b * 256 * 50176 + hp * 224 + wp;

  for (int cc = 0; cc < 4; ++cc) {
#pragma unroll 8
    for (int jj = 0; jj < 64; ++jj) {
      const int p = jj * 4 + wv;
      const int m = (base_r + ((p & 31) >> 3)) * 64 + (p >> 5) * 8 + (p & 7);
      xt[lane * 257 + p] = y[(long)m * 256 + cc * 64 + lane];
    }
    __syncthreads();
#pragma unroll 8
    for (int i = 0; i < 64; ++i)
      out[(long)(cc * 64 + i) * 50176 + woff] = xt[i * 257 + tid];
    __syncthreads();
  }
}

// ---------- launch ----------
extern "C" void kernel_launch(void* const* d_in, const int* in_sizes, int n_in,
                              void* d_out, int out_size, void* d_ws, size_t ws_size,
                              hipStream_t stream) {
  (void)in_sizes; (void)n_in; (void)out_size; (void)ws_size;
  const float* x     = (const float*)d_in[0];
  const float* qkvw  = (const float*)d_in[1];
  const float* projw = (const float*)d_in[2];
  const float* projb = (const float*)d_in[3];
  const float* rpb   = (const float*)d_in[4];
  const float* n1w   = (const float*)d_in[5];
  const float* n1b   = (const float*)d_in[6];
  const float* n2w   = (const float*)d_in[7];
  const float* n2b   = (const float*)d_in[8];
  const float* w1    = (const float*)d_in[9];
  const float* b1    = (const float*)d_in[10];
  const float* w2    = (const float*)d_in[11];
  const float* b2    = (const float*)d_in[12];

  char* ws = (char*)d_ws;
  u16*   hbuf   = (u16*)(ws);                  // 102,760,448 B : h, later h2
  u16*   qkvb   = (u16*)(ws + 102760448);      // 308,281,344 B : q|k|v
  u16*   abuf   = (u16*)(ws + 411041792);      // 102,760,448 B : attn out
  float* ybuf   = (float*)(ws + 513802240);    // 205,520,896 B : fp32 residual stream
  u16*   hidb   = (u16*)(ws + 102760448);      // 411,041,792 B : overlays qkv+attn (dead by then)
  u16*   qkvwb  = (u16*)(ws + 719323136);
  u16*   projwb = (u16*)(ws + 719716352);
  u16*   w1b    = (u16*)(ws + 719847424);
  u16*   w2b    = (u16*)(ws + 720371712);      // end: 720,896,000 B

  conv_weights<<<3072, 256, 0, stream>>>(qkvw, projw, w1, w2, qkvwb, projwb, w1b, w2b);
  ln1_win<<<784, 256, 0, stream>>>(x, n1w, n1b, hbuf, ybuf);
  gemm_bt<0, 3><<<2352, 512, 0, stream>>>(hbuf, qkvwb, 256, nullptr, nullptr, qkvb, nullptr, nullptr);
  attn_win<<<6272, 256, 0, stream>>>(qkvb, rpb, abuf);
  gemm_bt<1, 1><<<784, 512, 0, stream>>>(abuf, projwb, 256, ybuf, projb, hbuf, n2w, n2b);
  gemm_bt<2, 4><<<3136, 512, 0, stream>>>(hbuf, w1b, 256, nullptr, b1, hidb, nullptr, nullptr);
  gemm_bt<3, 1><<<784, 512, 0, stream>>>(hidb, w2b, 1024, ybuf, b2, nullptr, nullptr, nullptr);
  unwin<<<784, 256, 0, stream>>>(ybuf, (float*)d_out);
}

// Round 8
// 1124.585 us; speedup vs baseline: 1.5564x; 1.1061x over previous
//
#include <hip/hip_runtime.h>

typedef unsigned short u16;
typedef unsigned int   u32;
typedef __attribute__((ext_vector_type(8))) __bf16 bf16x8;
typedef __attribute__((ext_vector_type(4))) float  f32x4;
typedef __attribute__((ext_vector_type(4))) u16    u16x4;
typedef __attribute__((ext_vector_type(8))) u16    u16x8;

#define DEV __device__ __forceinline__

// ---------- helpers ----------
DEV u16 f2b(float f) {               // fp32 -> bf16 bits, RNE
  union { float f; u32 u; } a; a.f = f;
  const u32 u = a.u;
  return (u16)((u + 0x7fffu + ((u >> 16) & 1u)) >> 16);
}

// tanh-form GELU as x*sigmoid(1.5957691*(x+0.044715 x^3)); exp2-folded.
DEV float gelu_fast(float x) {
  const float x2 = x * x;
  const float t  = __builtin_fmaf(0.1029430f, x2, 2.3022150f);  // *log2(e) folded
  const float e  = __builtin_exp2f(x * t);
  const float r  = __builtin_amdgcn_rcpf(1.0f + e);
  return __builtin_fmaf(-x, r, x);   // x - x/(1+e) = x*sigmoid(z)
}

DEV void gload16(const void* g, void* l) {
  __builtin_amdgcn_global_load_lds(
      (const __attribute__((address_space(1))) void*)g,
      (__attribute__((address_space(3))) void*)l, 16, 0, 0);
}

// ---------- weight conversion (fp32 -> bf16) ----------
__global__ __launch_bounds__(256)
void conv_weights(const float* __restrict__ qkvw, const float* __restrict__ projw,
                  const float* __restrict__ w1,   const float* __restrict__ w2,
                  u16* __restrict__ dq, u16* __restrict__ dp,
                  u16* __restrict__ d1, u16* __restrict__ d2) {
  const int t = blockIdx.x * 256 + threadIdx.x;
  if (t < 196608)      dq[t]          = f2b(qkvw[t]);
  else if (t < 262144) dp[t - 196608] = f2b(projw[t - 196608]);
  else if (t < 524288) d1[t - 262144] = f2b(w1[t - 262144]);
  else                 d2[t - 524288] = f2b(w2[t - 524288]);
}

// ---------- window gather + LN1, 4 adjacent windows per block ----------
__global__ __launch_bounds__(256)
void ln1_win(const float* __restrict__ x, const float* __restrict__ w1,
             const float* __restrict__ b1, u16* __restrict__ hout,
             float* __restrict__ xwout) {
  __shared__ float xt[64 * 257];
  __shared__ float smean[256], srstd[256];
  const int tid = threadIdx.x, lane = tid & 63, wv = tid >> 6;
  const int g = blockIdx.x;
  const int b = g / 196, rem = g % 196;
  const int wh = rem / 7, wg = rem % 7;
  const int base_r = b * 784 + wh * 28 + wg * 4;
  const int pr = tid >> 5, pc = tid & 31;
  int hp = wh * 8 + 4 + pr; if (hp >= 224) hp -= 224;
  int wp = wg * 32 + 4 + pc; if (wp >= 224) wp -= 224;
  const long roff = (long)b * 256 * 50176 + hp * 224 + wp;

  float s = 0.f, q = 0.f;
  for (int cc = 0; cc < 4; ++cc) {
#pragma unroll 8
    for (int i = 0; i < 64; ++i) {
      const int c = cc * 64 + i;
      const float v = x[(long)c * 50176 + roff];
      xt[i * 257 + tid] = v;
      s += v; q += v * v;
    }
    __syncthreads();
#pragma unroll 8
    for (int jj = 0; jj < 64; ++jj) {
      const int p = jj * 4 + wv;
      const int m = (base_r + ((p & 31) >> 3)) * 64 + (p >> 5) * 8 + (p & 7);
      xwout[(long)m * 256 + cc * 64 + lane] = xt[lane * 257 + p];
    }
    __syncthreads();
  }
  const float mean = s * (1.f / 256.f);
  smean[tid] = mean;
  srstd[tid] = rsqrtf(q * (1.f / 256.f) - mean * mean + 1e-5f);
  __syncthreads();

  float wr_[4], br_[4];
#pragma unroll
  for (int cc = 0; cc < 4; ++cc) { wr_[cc] = w1[cc * 64 + lane]; br_[cc] = b1[cc * 64 + lane]; }
#pragma unroll 2
  for (int jj = 0; jj < 64; ++jj) {
    const int p = jj * 4 + wv;
    const int m = (base_r + ((p & 31) >> 3)) * 64 + (p >> 5) * 8 + (p & 7);
    const float mu = smean[p], rs = srstd[p];
#pragma unroll
    for (int cc = 0; cc < 4; ++cc) {
      const float v = xwout[(long)m * 256 + cc * 64 + lane];
      hout[(long)m * 256 + cc * 64 + lane] = f2b((v - mu) * rs * wr_[cc] + br_[cc]);
    }
  }
}

// ---------- 256x256x(BK=64) bf16 GEMM, B given as [N][K], 16 waves (4x4) ----------
// Wave tile 64x64 (acc 64 VGPR) -> 16 waves of ONE block resident = 4 waves/SIMD.
// 2-phase dbuf + counted vmcnt(4). T2 k-slot XOR swizzle. XCD chunk swizzle,
// column-fast decode. Operand-swapped MFMA except v sub-pass.
// EPI 0: qkv (NCOL=3): col_blk<2 -> q|k u16x4 along d; col_blk==2 -> v^T
// EPI 1: y += acc + bias (float4 RMW) + FUSED LN2 -> bout bf16 (NCOL=1)
// EPI 3: o = y + acc + bias; FUSED UNWINDOW -> oout (d_out, fp32) (NCOL=1)
// EPI 2: hidden = bf16(gelu(acc+b)), u16x4   (NCOL=4, ldc=1024)
template<int EPI, int NCOL>
__global__ __launch_bounds__(1024, 4)
void gemm_bt(const u16* __restrict__ A, const u16* __restrict__ Bw, const int K,
             float* __restrict__ fout, const float* __restrict__ bias,
             u16* __restrict__ bout,
             const float* __restrict__ lnw, const float* __restrict__ lnb,
             float* __restrict__ oout) {
  __shared__ __align__(16) u16 smem[65536];   // 128 KB
  u16* sA0 = smem;
  u16* sB0 = smem + 16384;
  u16* sA1 = smem + 32768;
  u16* sB1 = smem + 49152;

  const int tid  = threadIdx.x;
  const int lane = tid & 63;
  const int wid  = tid >> 6;       // 0..15
  const int wrr  = wid >> 2;       // 0..3  (row quarter)
  const int wcc  = wid & 3;        // 0..3  (col quarter)

  const int nwg = gridDim.x;
  const int bid = blockIdx.x;
  const int wg  = (bid & 7) * (nwg >> 3) + (bid >> 3);   // XCD chunk swizzle
  const int row_blk = wg / NCOL;                          // column-fast
  const int col_blk = wg - row_blk * NCOL;
  const int row0 = row_blk * 256;
  const int col0 = col_blk * 256;

  const f32x4 vzero = {0.f, 0.f, 0.f, 0.f};
  f32x4 acc[4][4];
#pragma unroll
  for (int i = 0; i < 4; ++i)
#pragma unroll
    for (int j = 0; j < 4; ++j) acc[i][j] = vzero;

  const int lrow = lane >> 3;
  const int lcol = ((lane & 7) << 3) ^ (lane & 56);  // pre-swizzled source k-offset
  const int l15  = lane & 15;
  const int l4   = lane >> 4;
  const int ksw  = (lane & 7) << 3;                  // ds_read swizzle

  const u16* pA = A  + (long)(row0 + wid * 8 + lrow) * K + lcol;
  const u16* pB = Bw + (long)(col0 + wid * 8 + lrow) * K + lcol;

#define STAGE_TILE(KT, DA, DB)                                          \
  {                                                                     \
    _Pragma("unroll")                                                   \
    for (int ch = 0; ch < 2; ++ch) {                                    \
      gload16(pA + (long)(ch * 128) * K + (KT), (DA) + (ch * 128 + wid * 8) * 64); \
      gload16(pB + (long)(ch * 128) * K + (KT), (DB) + (ch * 128 + wid * 8) * 64); \
    }                                                                   \
  }

#define COMPUTE_TILE(SA, SB, SWAP)                                                      \
  {                                                                                     \
    _Pragma("unroll")                                                                   \
    for (int kk = 0; kk < 2; ++kk) {                                                    \
      bf16x8 af[4], bfv[4];                                                             \
      _Pragma("unroll")                                                                 \
      for (int mi = 0; mi < 4; ++mi)                                                    \
        af[mi] = *(const bf16x8*)((SA) + (wrr * 64 + mi * 16 + l15) * 64 +              \
                                  ((kk * 32 + l4 * 8) ^ ksw));                          \
      _Pragma("unroll")                                                                 \
      for (int nj = 0; nj < 4; ++nj)                                                    \
        bfv[nj] = *(const bf16x8*)((SB) + (wcc * 64 + nj * 16 + l15) * 64 +             \
                                   ((kk * 32 + l4 * 8) ^ ksw));                         \
      _Pragma("unroll")                                                                 \
      for (int mi = 0; mi < 4; ++mi)                                                    \
        _Pragma("unroll")                                                               \
        for (int nj = 0; nj < 4; ++nj) {                                                \
          if (SWAP)                                                                     \
            acc[mi][nj] = __builtin_amdgcn_mfma_f32_16x16x32_bf16(bfv[nj], af[mi],      \
                                                                  acc[mi][nj], 0, 0, 0);\
          else                                                                          \
            acc[mi][nj] = __builtin_amdgcn_mfma_f32_16x16x32_bf16(af[mi], bfv[nj],      \
                                                                  acc[mi][nj], 0, 0, 0);\
        }                                                                               \
    }                                                                                   \
  }

// counted-vmcnt 2-phase k-loop: one STAGE = 4 per-thread loads -> vmcnt(4)
#define KLOOP(SWAP)                                                  \
  {                                                                  \
    const int nt = K >> 6;                                           \
    STAGE_TILE(0, sA0, sB0);                                         \
    int cur = 0;                                                     \
    for (int t = 0; t < nt; ++t) {                                   \
      u16* cA = cur ? sA1 : sA0;                                     \
      u16* cB = cur ? sB1 : sB0;                                     \
      u16* nA = cur ? sA0 : sA1;                                     \
      u16* nB = cur ? sB0 : sB1;                                     \
      if (t + 1 < nt) {                                              \
        STAGE_TILE((t + 1) << 6, nA, nB);                            \
        asm volatile("s_waitcnt vmcnt(4)" ::: "memory");             \
      } else {                                                       \
        asm volatile("s_waitcnt vmcnt(0)" ::: "memory");             \
      }                                                              \
      __builtin_amdgcn_s_barrier();                                  \
      asm volatile("" ::: "memory");                                 \
      COMPUTE_TILE(cA, cB, SWAP);                                    \
      asm volatile("" ::: "memory");                                 \
      __builtin_amdgcn_s_barrier();                                  \
      cur ^= 1;                                                      \
    }                                                                \
  }

  if (EPI == 0 && col_blk == 2) {
    // ---- v: unswapped orientation, v^T scatter (lane=n(d), reg=m(ii)) ----
    KLOOP(0);
#pragma unroll
    for (int mi = 0; mi < 4; ++mi) {
      const int mb = row0 + wrr * 64 + mi * 16 + (l4 << 2);
      const int rrg = mb >> 6, ii = mb & 63;
#pragma unroll
      for (int nj = 0; nj < 4; ++nj) {
        const int n = 512 + wcc * 64 + nj * 16 + l15;
        const int hh = (n >> 5) & 7, d = n & 31;
        u16x4 p;
#pragma unroll
        for (int reg = 0; reg < 4; ++reg) p[reg] = f2b(acc[mi][nj][reg]);
        *(u16x4*)(bout + 102760448L + (long)((rrg * 8 + hh) * 32 + d) * 64 + ii) = p;
      }
    }
    return;
  }

  KLOOP(1);

#undef STAGE_TILE
#undef COMPUTE_TILE
#undef KLOOP

  if (EPI == 0) {
    // q|k scatter, swapped orientation: lane=m, reg=n(d)
#pragma unroll
    for (int mi = 0; mi < 4; ++mi) {
      const int m = row0 + wrr * 64 + mi * 16 + l15;
      const int rr = m >> 6, ii = m & 63;
#pragma unroll
      for (int nj = 0; nj < 4; ++nj) {
        const int n = col0 + wcc * 64 + nj * 16 + (l4 << 2);
        const int s = n >> 8, hh = (n >> 5) & 7, d = n & 31;
        u16x4 p;
#pragma unroll
        for (int reg = 0; reg < 4; ++reg) p[reg] = f2b(acc[mi][nj][reg]);
        *(u16x4*)(bout + (long)s * 51380224L +
                  (long)((rr * 8 + hh) * 64 + ii) * 32 + d) = p;
      }
    }
  } else if (EPI == 1) {
    // y += acc + bias (float4 RMW), then fused LN2 -> bout (bf16 [m][256])
    f32x4 b4[4];
#pragma unroll
    for (int nj = 0; nj < 4; ++nj)
      b4[nj] = *(const f32x4*)(bias + wcc * 64 + nj * 16 + (l4 << 2));
    float sS[4], sQ[4];
#pragma unroll
    for (int mi = 0; mi < 4; ++mi) {
      const int m = row0 + wrr * 64 + mi * 16 + l15;
      float* yrow = fout + (long)m * 256;
      float s = 0.f, q = 0.f;
#pragma unroll
      for (int nj = 0; nj < 4; ++nj) {
        const int n = wcc * 64 + nj * 16 + (l4 << 2);
        f32x4 o = *(f32x4*)(yrow + n);
#pragma unroll
        for (int reg = 0; reg < 4; ++reg) {
          o[reg] += acc[mi][nj][reg] + b4[nj][reg];
          s += o[reg]; q += o[reg] * o[reg];
        }
        *(f32x4*)(yrow + n) = o;
        acc[mi][nj] = o;
      }
      s += __shfl_xor(s, 16); s += __shfl_xor(s, 32);
      q += __shfl_xor(q, 16); q += __shfl_xor(q, 32);
      sS[mi] = s; sQ[mi] = q;
    }
    float* ps = (float*)smem;          // [256 rows][4 wcc]
    float* pq = ps + 1024;
    __syncthreads();
    if (lane < 16) {
#pragma unroll
      for (int mi = 0; mi < 4; ++mi) {
        const int idx = ((wrr * 4 + mi) * 16 + l15) * 4 + wcc;
        ps[idx] = sS[mi]; pq[idx] = sQ[mi];
      }
    }
    __syncthreads();
#pragma unroll
    for (int mi = 0; mi < 4; ++mi) {
      const int m = row0 + wrr * 64 + mi * 16 + l15;
      const int base = ((wrr * 4 + mi) * 16 + l15) * 4;
      const float S = ps[base] + ps[base + 1] + ps[base + 2] + ps[base + 3];
      const float Q = pq[base] + pq[base + 1] + pq[base + 2] + pq[base + 3];
      const float mean = S * (1.f / 256.f);
      const float rstd = rsqrtf(Q * (1.f / 256.f) - mean * mean + 1e-5f);
#pragma unroll
      for (int nj = 0; nj < 4; ++nj) {
        const int n = wcc * 64 + nj * 16 + (l4 << 2);
        const f32x4 w4 = *(const f32x4*)(lnw + n);
        const f32x4 c4 = *(const f32x4*)(lnb + n);
        u16x4 p;
#pragma unroll
        for (int reg = 0; reg < 4; ++reg)
          p[reg] = f2b((acc[mi][nj][reg] - mean) * rstd * w4[reg] + c4[reg]);
        *(u16x4*)(bout + (long)m * 256 + n) = p;
      }
    }
  } else if (EPI == 3) {
    // o = y + acc + bias (no ybuf writeback); fused un-window -> oout (d_out)
    f32x4 b4[4];
#pragma unroll
    for (int nj = 0; nj < 4; ++nj)
      b4[nj] = *(const f32x4*)(bias + wcc * 64 + nj * 16 + (l4 << 2));
#pragma unroll
    for (int mi = 0; mi < 4; ++mi) {
      const int m = row0 + wrr * 64 + mi * 16 + l15;
      const float* yrow = fout + (long)m * 256;
#pragma unroll
      for (int nj = 0; nj < 4; ++nj) {
        const int n = wcc * 64 + nj * 16 + (l4 << 2);
        const f32x4 yv = *(const f32x4*)(yrow + n);
#pragma unroll
        for (int reg = 0; reg < 4; ++reg)
          acc[mi][nj][reg] += yv[reg] + b4[nj][reg];
      }
    }
    // block -> (b, wh, wg); 256 rows = 4 windows = 8 img rows x 32 img cols
    const int g = row0 >> 8;
    const int b = g / 196, rem = g % 196;
    const int wh = rem / 7, wg2 = rem % 7;
    float* tp = (float*)smem;          // [64 c][256 px''], XOR-swizzled
    const int pidx = tid & 255, cgrp = tid >> 8;
    const int pr = pidx >> 5, pc = pidx & 31;
    int hp = wh * 8 + 4 + pr; if (hp >= 224) hp -= 224;
    int wp = wg2 * 32 + 4 + pc; if (wp >= 224) wp -= 224;
    float* ob = oout + (long)b * 256 * 50176 + hp * 224 + wp;
    const int pxr = 4 * (pr * 8 + (pc & 7)) + (pc >> 3);
#pragma unroll
    for (int cc = 0; cc < 4; ++cc) {
      __syncthreads();
      if (wcc == cc) {
#pragma unroll
        for (int mi = 0; mi < 4; ++mi) {
          const int pxw = (4 * (mi * 16 + l15) + wrr) ^ l4;
#pragma unroll
          for (int nj = 0; nj < 4; ++nj)
#pragma unroll
            for (int reg = 0; reg < 4; ++reg)
              tp[(nj * 16 + (l4 << 2) + reg) * 256 + pxw] = acc[mi][nj][reg];
        }
      }
      __syncthreads();
#pragma unroll 4
      for (int j = 0; j < 16; ++j) {
        const int c_local = cgrp * 16 + j;
        ob[(long)(cc * 64 + c_local) * 50176] =
            tp[c_local * 256 + (pxr ^ ((j >> 2) & 3))];
      }
    }
  } else if (EPI == 2) {
    // hidden = bf16(gelu(acc+bias)), u16x4 along n, ldc=1024
    f32x4 b4[4];
#pragma unroll
    for (int nj = 0; nj < 4; ++nj)
      b4[nj] = *(const f32x4*)(bias + col0 + wcc * 64 + nj * 16 + (l4 << 2));
#pragma unroll
    for (int mi = 0; mi < 4; ++mi) {
      const int m = row0 + wrr * 64 + mi * 16 + l15;
#pragma unroll
      for (int nj = 0; nj < 4; ++nj) {
        const int n = col0 + wcc * 64 + nj * 16 + (l4 << 2);
        u16x4 p;
#pragma unroll
        for (int reg = 0; reg < 4; ++reg)
          p[reg] = f2b(gelu_fast(acc[mi][nj][reg] + b4[nj][reg]));
        *(u16x4*)(bout + (long)m * 1024 + n) = p;
      }
    }
  }
}

// ---------- per-window attention: 1 wave = 1 head ----------
// P stored bf16 in per-wave LDS (8 KB) with XOR swizzle j ^= (i&7)<<3.
// PV computed operand-swapped: O^T = mfma(V^T, P) -> u16x4 stores along d.
__global__ __launch_bounds__(256)
void attn_win(const u16* __restrict__ qkv, const float* __restrict__ rpb,
              u16* __restrict__ aout) {
  __shared__ u16 Pl[4][4096];
  __shared__ float srpb[1800];
  const int tid = threadIdx.x, lane = tid & 63, wv = tid >> 6;
  const int bid = blockIdx.x;
  const int r = bid >> 1;
  const int h = (bid & 1) * 4 + wv;
  for (int i = tid; i < 1800; i += 256) srpb[i] = rpb[i];
  __syncthreads();

  // reference quirk: jnp.repeat(mask, B, axis=0) -> window r uses mask[r/4]
  const int midx = r >> 2;
  const int wh = midx / 28, ww = midx % 28;
  const int l15 = lane & 15, l4 = lane >> 4;

  u16* Pw = &Pl[wv][0];
  const long hb = (long)(r * 8 + h) * 2048;
  const u16* qh = qkv + hb;
  const u16* kh = qkv + 51380224 + hb;
  const u16* vh = qkv + 102760448 + hb;

  int rj[4], cj[4], labj[4];
#pragma unroll
  for (int nj = 0; nj < 4; ++nj) {
    const int j = nj * 16 + l15;
    rj[nj] = j >> 3; cj[nj] = j & 7;
    const int hp = wh * 8 + rj[nj], wp = ww * 8 + cj[nj];
    const int lh = (hp < 216) ? 0 : ((hp < 220) ? 1 : 2);
    const int lw = (wp < 216) ? 0 : ((wp < 220) ? 1 : 2);
    labj[nj] = lh * 3 + lw;
  }

  const f32x4 vzero = {0.f, 0.f, 0.f, 0.f};

  bf16x8 qf[4], kf[4];
#pragma unroll
  for (int mi = 0; mi < 4; ++mi)
    qf[mi] = *(const bf16x8*)(qh + (mi * 16 + l15) * 32 + l4 * 8);
#pragma unroll
  for (int nj = 0; nj < 4; ++nj)
    kf[nj] = *(const bf16x8*)(kh + (nj * 16 + l15) * 32 + l4 * 8);

  f32x4 S[4][4];
#pragma unroll
  for (int mi = 0; mi < 4; ++mi)
#pragma unroll
    for (int nj = 0; nj < 4; ++nj)
      S[mi][nj] = __builtin_amdgcn_mfma_f32_16x16x32_bf16(qf[mi], kf[nj], vzero, 0, 0, 0);

  // softmax (row-parallel over 16-lane groups) + normalized bf16 P -> LDS
#pragma unroll
  for (int mi = 0; mi < 4; ++mi)
#pragma unroll
    for (int reg = 0; reg < 4; ++reg) {
      const int i = mi * 16 + (l4 << 2) + reg;
      const int ri = i >> 3, ci = i & 7;
      const int hp = wh * 8 + ri, wp = ww * 8 + ci;
      const int lh = (hp < 216) ? 0 : ((hp < 220) ? 1 : 2);
      const int lw = (wp < 216) ? 0 : ((wp < 220) ? 1 : 2);
      const int li = lh * 3 + lw;
      float v[4];
#pragma unroll
      for (int nj = 0; nj < 4; ++nj) {
        const int idx = (ri - rj[nj] + 7) * 15 + (ci - cj[nj] + 7);
        v[nj] = S[mi][nj][reg] * 0.17677669529663687f + srpb[idx * 8 + h]
              + ((li != labj[nj]) ? -100.0f : 0.0f);
      }
      float mx = fmaxf(fmaxf(v[0], v[1]), fmaxf(v[2], v[3]));
      mx = fmaxf(mx, __shfl_xor(mx, 1));
      mx = fmaxf(mx, __shfl_xor(mx, 2));
      mx = fmaxf(mx, __shfl_xor(mx, 4));
      mx = fmaxf(mx, __shfl_xor(mx, 8));
      float sum = 0.f;
#pragma unroll
      for (int nj = 0; nj < 4; ++nj) { v[nj] = __expf(v[nj] - mx); sum += v[nj]; }
      sum += __shfl_xor(sum, 1);
      sum += __shfl_xor(sum, 2);
      sum += __shfl_xor(sum, 4);
      sum += __shfl_xor(sum, 8);
      const float rinv = __builtin_amdgcn_rcpf(sum);
      const int sw = (i & 7) << 3;
#pragma unroll
      for (int nj = 0; nj < 4; ++nj)
        Pw[i * 64 + ((nj * 16 + l15) ^ sw)] = f2b(v[nj] * rinv);
    }

  // PV: O^T = mfma(V^T, P) — per-wave LDS, no barrier needed
  f32x4 OT[2][4];
#pragma unroll
  for (int td = 0; td < 2; ++td)
#pragma unroll
    for (int ti = 0; ti < 4; ++ti) OT[td][ti] = vzero;

  const int rsw = (l15 & 7) << 3;
#pragma unroll
  for (int kk = 0; kk < 2; ++kk) {
    bf16x8 pf[4], vf[2];
#pragma unroll
    for (int ti = 0; ti < 4; ++ti)
      pf[ti] = *(const bf16x8*)(Pw + (ti * 16 + l15) * 64 + ((kk * 32 + l4 * 8) ^ rsw));
#pragma unroll
    for (int td = 0; td < 2; ++td)
      vf[td] = *(const bf16x8*)(vh + (td * 16 + l15) * 64 + kk * 32 + l4 * 8);
#pragma unroll
    for (int td = 0; td < 2; ++td)
#pragma unroll
      for (int ti = 0; ti < 4; ++ti)
        OT[td][ti] = __builtin_amdgcn_mfma_f32_16x16x32_bf16(vf[td], pf[ti], OT[td][ti], 0, 0, 0);
  }

  // write: lane holds O[i=ti*16+l15][d=td*16+4*l4+reg] -> u16x4 along d
#pragma unroll
  for (int td = 0; td < 2; ++td)
#pragma unroll
    for (int ti = 0; ti < 4; ++ti) {
      const int i = ti * 16 + l15;
      const int d0 = td * 16 + (l4 << 2);
      u16x4 p;
#pragma unroll
      for (int reg = 0; reg < 4; ++reg) p[reg] = f2b(OT[td][ti][reg]);
      *(u16x4*)(aout + (long)(r * 64 + i) * 256 + h * 32 + d0) = p;
    }
}

// ---------- launch ----------
extern "C" void kernel_launch(void* const* d_in, const int* in_sizes, int n_in,
                              void* d_out, int out_size, void* d_ws, size_t ws_size,
                              hipStream_t stream) {
  (void)in_sizes; (void)n_in; (void)out_size; (void)ws_size;
  const float* x     = (const float*)d_in[0];
  const float* qkvw  = (const float*)d_in[1];
  const float* projw = (const float*)d_in[2];
  const float* projb = (const float*)d_in[3];
  const float* rpb   = (const float*)d_in[4];
  const float* n1w   = (const float*)d_in[5];
  const float* n1b   = (const float*)d_in[6];
  const float* n2w   = (const float*)d_in[7];
  const float* n2b   = (const float*)d_in[8];
  const float* w1    = (const float*)d_in[9];
  const float* b1    = (const float*)d_in[10];
  const float* w2    = (const float*)d_in[11];
  const float* b2    = (const float*)d_in[12];

  char* ws = (char*)d_ws;
  u16*   hbuf   = (u16*)(ws);                  // 102,760,448 B : h, later h2
  u16*   qkvb   = (u16*)(ws + 102760448);      // 308,281,344 B : q|k|v
  u16*   abuf   = (u16*)(ws + 411041792);      // 102,760,448 B : attn out
  float* ybuf   = (float*)(ws + 513802240);    // 205,520,896 B : fp32 residual stream
  u16*   hidb   = (u16*)(ws + 102760448);      // 411,041,792 B : overlays qkv+attn (dead by then)
  u16*   qkvwb  = (u16*)(ws + 719323136);
  u16*   projwb = (u16*)(ws + 719716352);
  u16*   w1b    = (u16*)(ws + 719847424);
  u16*   w2b    = (u16*)(ws + 720371712);      // end: 720,896,000 B

  conv_weights<<<3072, 256, 0, stream>>>(qkvw, projw, w1, w2, qkvwb, projwb, w1b, w2b);
  ln1_win<<<784, 256, 0, stream>>>(x, n1w, n1b, hbuf, ybuf);
  gemm_bt<0, 3><<<2352, 1024, 0, stream>>>(hbuf, qkvwb, 256, nullptr, nullptr, qkvb, nullptr, nullptr, nullptr);
  attn_win<<<6272, 256, 0, stream>>>(qkvb, rpb, abuf);
  gemm_bt<1, 1><<<784, 1024, 0, stream>>>(abuf, projwb, 256, ybuf, projb, hbuf, n2w, n2b, nullptr);
  gemm_bt<2, 4><<<3136, 1024, 0, stream>>>(hbuf, w1b, 256, nullptr, b1, hidb, nullptr, nullptr, nullptr);
  gemm_bt<3, 1><<<784, 1024, 0, stream>>>(hidb, w2b, 1024, ybuf, b2, nullptr, nullptr, nullptr, (float*)d_out);
}